// Round 12
// baseline (229.694 us; speedup 1.0000x reference)
//
#include <hip/hip_runtime.h>

#define BB 128
#define TT 224
#define LL 224

typedef float v2f __attribute__((ext_vector_type(2)));

__device__ __forceinline__ float rcpf(float x){ return __builtin_amdgcn_rcpf(x); }

#if __has_builtin(__builtin_amdgcn_exp2f)
#define EXP2(x) __builtin_amdgcn_exp2f(x)
#else
#define EXP2(x) __expf((x)*0.6931471805599453f)
#endif

#if __has_attribute(amdgpu_num_vgpr)
#define VGPRHINT __attribute__((amdgpu_num_vgpr(256)))
#else
#define VGPRHINT
#endif

// DPP row rotate-right by N: dst[k] = src[(k-N)&15] within each 16-lane row
template<int N>
__device__ __forceinline__ float rorN(float x){
  int xi = __builtin_bit_cast(int, x);
  xi = __builtin_amdgcn_update_dpp(xi, xi, 0x120 + N, 0xf, 0xf, false);
  return __builtin_bit_cast(float, xi);
}

// v_permlane32_swap_b32: with a==b==x -> a'=low-half bcast, b'=high-half bcast
__device__ __forceinline__ void swap32(float& a, float& b){
  asm volatile("s_nop 1\n\tv_permlane32_swap_b32 %0, %1\n\ts_nop 1"
               : "+v"(a), "+v"(b));
}

// ---------------- K1: conv chain (both branches) + Wt = fcw3@fcw2 ----------
__global__ __launch_bounds__(256) void conv_chain_kernel(const float* __restrict__ x,
    const float* __restrict__ c1w1, const float* __restrict__ c1b1,
    const float* __restrict__ c1w2, const float* __restrict__ c1b2,
    const float* __restrict__ c2w1, const float* __restrict__ c2b1,
    const float* __restrict__ c2w2, const float* __restrict__ c2b2,
    float* __restrict__ y,
    const float* __restrict__ fcw3, const float* __restrict__ fcw2,
    float* __restrict__ Wtb)
{
  __shared__ float xs[4*224];
  __shared__ float c1s[4*56];
  int gid = blockIdx.x;
  int tid = threadIdx.x;

  if (gid >= 14336){
    int idx = (gid - 14336)*256 + tid;       // < 9216
    int o = idx >> 10, n = idx & 1023;
    float acc = 0.f;
    for (int p=0;p<192;p++) acc += fcw3[o*192+p]*fcw2[(size_t)p*1024+n];
    Wtb[idx] = acc;
    return;
  }

  int branch = (gid >= 7168);
  const float* w1 = branch ? c2w1 : c1w1;
  const float* w2 = branch ? c2w2 : c1w2;
  float b1  = branch ? c2b1[0] : c1b1[0];
  float b2v = branch ? c2b2[0] : c1b2[0];

  if (tid < 224){
    *(float4*)&xs[tid*4] = *((const float4*)x + (size_t)gid*224 + tid);
  }
  __syncthreads();
  if (tid < 224){
    int rr = tid / 56, cj = tid - rr*56;
    int base = 4*cj - 2;
    const float* xr = &xs[rr*224];
    float s = b1;
    #pragma unroll
    for (int kk=0;kk<8;kk++){
      int xi = base + kk;
      float xv = (xi>=0 && xi<224) ? xr[xi] : 0.f;
      s += xv * w1[kk];
    }
    c1s[rr*56 + cj] = fmaxf(s, 0.f);
  }
  __syncthreads();
  if (tid < 112){
    int rr = tid / 28, j = tid - rr*28;
    const float* cr = &c1s[rr*56];
    float o = b2v;
    #pragma unroll
    for (int pi=0;pi<3;pi++){
      int p = j - 1 + pi;
      float pool = 0.f;
      if (p>=0 && p<28){
        int i0 = 2*p - 1;
        float m = -1e30f;
        #pragma unroll
        for (int q=0;q<4;q++){
          int ii = i0+q;
          if (ii>=0 && ii<56) m = fmaxf(m, cr[ii]);
        }
        pool = fmaxf(m, 0.f);
      }
      o += pool * w2[pi];
    }
    y[(size_t)gid*112 + tid] = fmaxf(o, 0.f);
  }
}

// -------- K2: pre-gate GEMM (batch-major threads) + FC blocks first ------
template<int D, int PHASE>
__global__ __launch_bounds__(256) void pregate_fused_kernel(
    const float* __restrict__ in, int inStrideBranch,
    const float* __restrict__ wihA, const float* __restrict__ biasA,
    const float* __restrict__ wihB, const float* __restrict__ biasB,
    float* __restrict__ pre,
    const float* __restrict__ fcw1, const float* __restrict__ fcw2,
    const float* __restrict__ fcw3, const float* __restrict__ fcb1,
    const float* __restrict__ fcb2, const float* __restrict__ fcb3,
    const float* __restrict__ Wtb,
    float* __restrict__ wpart, float* __restrict__ Wc, float* __restrict__ BC)
{
  __shared__ float sb[48*28 + 48];
  int gb  = blockIdx.x;
  int tid = threadIdx.x;
  const int NFC = (PHASE==0) ? 337 : 189;

  if (gb < NFC){
    if (PHASE == 0){
      if (gb < 336){
        int s = gb / 21, jb = gb % 21;
        for (int i = tid; i < 576; i += 256){
          sb[i] = Wtb[(i>>6)*1024 + s*64 + (i&63)];
        }
        __syncthreads();
        int j = jb*256 + tid;
        float acc[9];
        #pragma unroll
        for (int o=0;o<9;o++) acc[o]=0.f;
        int nbase = s*64;
        #pragma unroll 4
        for (int n=0;n<64;n++){
          float v = fcw1[(size_t)(nbase+n)*5376 + j];
          #pragma unroll
          for (int o=0;o<9;o++) acc[o] += sb[o*64+n]*v;
        }
        #pragma unroll
        for (int o=0;o<9;o++) wpart[((size_t)s*9+o)*5376 + j] = acc[o];
      } else {
        if (tid < 192){
          const float* f2 = fcw2 + (size_t)tid*1024;
          float acc = 0.f;
          for (int n=0;n<1024;n++) acc += f2[n]*fcb1[n];
          sb[tid] = acc;
        }
        __syncthreads();
        if (tid < 9){
          float acc = fcb3[tid];
          const float* f3 = fcw3 + tid*192;
          for (int p=0;p<192;p++) acc += f3[p]*(fcb2[p]+sb[p]);
          BC[tid] = acc;
        }
      }
    } else {
      int idx = gb*256 + tid;   // 189*256 = 48384 exactly
      float a = 0.f;
      #pragma unroll
      for (int s=0;s<16;s++) a += wpart[(size_t)s*48384 + idx];
      Wc[idx] = a;
    }
    return;
  }

  int pgb = gb - NFC;
  float* wL = sb;
  float* bL = sb + 48*D;
  int r = pgb / 1344;
  int lin = (pgb % 1344)*256 + tid;
  int br = r>>1, dir = r&1;
  const float* wih  = (br ? wihB  : wihA)  + dir*48*D;
  const float* bias = (br ? biasB : biasA) + dir*48;
  for (int i = tid; i < 48*D; i += 256) wL[i]=wih[i];
  if (tid < 48) bL[tid]=bias[tid];
  __syncthreads();
  int tb = lin/12;  int k = lin - tb*12;   // tb = b*224 + t (batch-major)
  const float* rowp = in + (size_t)br*inStrideBranch + (size_t)tb*D;
  float aI=bL[k], aF=bL[12+k], aG=bL[24+k], aO=bL[36+k];
  const float4* rp4 = (const float4*)rowp;
  #pragma unroll
  for (int d4=0; d4<D/4; d4++){
    float4 xv = rp4[d4];
    float4 wI = *(const float4*)&wL[(0*12+k)*D + d4*4];
    float4 wF = *(const float4*)&wL[(1*12+k)*D + d4*4];
    float4 wG = *(const float4*)&wL[(2*12+k)*D + d4*4];
    float4 wO = *(const float4*)&wL[(3*12+k)*D + d4*4];
    aI += xv.x*wI.x + xv.y*wI.y + xv.z*wI.z + xv.w*wI.w;
    aF += xv.x*wF.x + xv.y*wF.y + xv.z*wF.z + xv.w*wF.w;
    aG += xv.x*wG.x + xv.y*wG.y + xv.z*wG.z + xv.w*wG.w;
    aO += xv.x*wO.x + xv.y*wO.y + xv.z*wO.z + xv.w*wO.w;
  }
  float4* o = (float4*)(pre + (size_t)r*(TT*BB*48) + (size_t)tb*48 + k*4);
  *o = make_float4(aI,aF,aG,aO);
}

// ---------------- K3: LSTM scan — template A/B: DUAL=0 single (R11), ------
// DUAL=1 two same-run chains per wave (shared weights/addressing).
#define STEPD(P, HV, CST, HB, SS) { \
  float x1=rorN<1>(HV), x2=rorN<2>(HV), x3=rorN<3>(HV), x4=rorN<4>(HV), \
        x5=rorN<5>(HV), x6=rorN<6>(HV), x7=rorN<7>(HV), x8=rorN<8>(HV), \
        x9=rorN<9>(HV), x10=rorN<10>(HV), x11=rorN<11>(HV), x12=rorN<12>(HV), \
        x13=rorN<13>(HV), x14=rorN<14>(HV), x15=rorN<15>(HV); \
  v2f a0 = (P); \
  a0 += w[0]*(v2f){HV,HV};   a0 += w[1]*(v2f){x1,x1};   a0 += w[2]*(v2f){x2,x2};   a0 += w[3]*(v2f){x3,x3}; \
  v2f a1 = w[4]*(v2f){x4,x4};   a1 += w[5]*(v2f){x5,x5};   a1 += w[6]*(v2f){x6,x6};   a1 += w[7]*(v2f){x7,x7}; \
  v2f a2 = w[8]*(v2f){x8,x8};   a2 += w[9]*(v2f){x9,x9};   a2 += w[10]*(v2f){x10,x10}; a2 += w[11]*(v2f){x11,x11}; \
  v2f a3 = w[12]*(v2f){x12,x12}; a3 += w[13]*(v2f){x13,x13}; a3 += w[14]*(v2f){x14,x14}; a3 += w[15]*(v2f){x15,x15}; \
  v2f gg = (a0+a1)+(a2+a3); \
  v2f m  = gg*kmul; \
  v2f e  = { EXP2(m.x), EXP2(m.y) }; \
  e += (v2f){1.f,1.f}; \
  v2f d  = { rcpf(e.x), rcpf(e.y) }; \
  v2f res = ca*d + cb; \
  float p0 = res.x, p1 = res.x; swap32(p0, p1); \
  float q0 = res.y, q1 = res.y; swap32(q0, q1); \
  CST = fmaf(q0, CST, p0*p1); \
  float et = EXP2(CST*2.885390082f); \
  float dt = rcpf(et+1.f); \
  HV = q1*fmaf(-2.f, dt, 1.f); \
  HB[SS] = HV; }

#define FLUSHD(HB, OP) { \
  if (doSt){ \
    _Pragma("unroll") \
    for (int q=0;q<8;q++) OP[q*ostep] = HB[q]; \
  } \
  OP += 8*ostep; }

template<int DUAL>
__global__ __launch_bounds__(64) __attribute__((amdgpu_waves_per_eu(1,1))) VGPRHINT
void lstm_kernel(const float* __restrict__ pre,
    const float* __restrict__ whhA, const float* __restrict__ whhB,
    float* __restrict__ out)
{
  int blk  = blockIdx.x;
  int lane = threadIdx.x;
  int u    = lane & 15;
  int bh   = (lane >> 4) & 1;
  int rbit = lane >> 5;
  int keff = (u < 12) ? u : 11;

  int r  = DUAL ? (blk >> 5) : (blk >> 6);     // run 0..3
  int br = r >> 1, dir = r & 1;
  const float* whh = (br ? whhB : whhA) + dir*48*12;

  v2f w[16];
  #pragma unroll
  for (int rr=0; rr<16; rr++){
    int j = (u - rr) & 15;
    bool vld = (j < 12) && (u < 12);
    int uw = (u < 12) ? u : 0;
    int jw = (j < 12) ? j : 0;
    float wa = whh[((rbit?24:0)  + uw)*12 + jw];   // g : i
    float wb = whh[((rbit?36:12) + uw)*12 + jw];   // o : f
    w[rr] = (v2f){ vld ? wa : 0.f, vld ? wb : 0.f };
  }
  const v2f kmul = rbit ? (v2f){2.885390082f, -1.442695041f}
                        : (v2f){-1.442695041f, -1.442695041f};
  const v2f ca   = rbit ? (v2f){-2.f, 1.f} : (v2f){1.f, 1.f};
  const v2f cb   = rbit ? (v2f){ 1.f, 0.f} : (v2f){0.f, 0.f};

  const int sstep = dir ? -48 : 48;
  const int scb0  = dir ? 223*48 : 0;
  const int ostep = dir ? -24 : 24;
  const bool doSt = (rbit==0) && (u < 12);

  if constexpr (DUAL == 0) {
    int b = (blk & 63)*2 + bh;
    const float* preR = pre + (size_t)r*(TT*BB*48) + (size_t)b*(TT*48) + keff*4 + rbit*2;
    int scb = scb0;

    v2f pcur[8], pnext[8];
    #pragma unroll
    for (int i=0;i<8;i++) pcur[i]  = *(const v2f*)(preR + scb +  i   *sstep);
    #pragma unroll
    for (int i=0;i<8;i++) pnext[i] = *(const v2f*)(preR + scb + (i+8)*sstep);
    int lb = scb + 16*sstep;

    float hv = 0.f, cst = 0.f;
    float hbuf[8];
    float* outP = out + (size_t)br*(BB*TT*24) + (size_t)b*TT*24 + dir*12 + u
                + (size_t)(dir ? 223 : 0)*24;

    for (int c=0;c<14;c++){
      STEPD(pcur[0],hv,cst,hbuf,0) STEPD(pcur[1],hv,cst,hbuf,1)
      STEPD(pcur[2],hv,cst,hbuf,2) STEPD(pcur[3],hv,cst,hbuf,3)
      STEPD(pcur[4],hv,cst,hbuf,4) STEPD(pcur[5],hv,cst,hbuf,5)
      STEPD(pcur[6],hv,cst,hbuf,6) STEPD(pcur[7],hv,cst,hbuf,7)
      FLUSHD(hbuf, outP)
      if (c < 13){
        #pragma unroll
        for (int i=0;i<8;i++) pcur[i] = *(const v2f*)(preR + lb + i*sstep);
        lb += 8*sstep;
      }
      STEPD(pnext[0],hv,cst,hbuf,0) STEPD(pnext[1],hv,cst,hbuf,1)
      STEPD(pnext[2],hv,cst,hbuf,2) STEPD(pnext[3],hv,cst,hbuf,3)
      STEPD(pnext[4],hv,cst,hbuf,4) STEPD(pnext[5],hv,cst,hbuf,5)
      STEPD(pnext[6],hv,cst,hbuf,6) STEPD(pnext[7],hv,cst,hbuf,7)
      FLUSHD(hbuf, outP)
      if (c < 13){
        #pragma unroll
        for (int i=0;i<8;i++) pnext[i] = *(const v2f*)(preR + lb + i*sstep);
        lb += 8*sstep;
      }
    }
  } else {
    // DUAL: chains A (batch bA) and B (batch bA+2), same run -> shared w,
    // stride, mask; B's addresses = A's + fixed offset.
    int bA = (blk & 31)*4 + bh;
    const float* preA = pre + (size_t)r*(TT*BB*48) + (size_t)bA*(TT*48) + keff*4 + rbit*2;
    const float* preB = preA + 2*(TT*48);
    int scb = scb0;

    v2f pcA[8], pnA[8], pcB[8], pnB[8];
    #pragma unroll
    for (int i=0;i<8;i++) pcA[i] = *(const v2f*)(preA + scb +  i   *sstep);
    #pragma unroll
    for (int i=0;i<8;i++) pnA[i] = *(const v2f*)(preA + scb + (i+8)*sstep);
    #pragma unroll
    for (int i=0;i<8;i++) pcB[i] = *(const v2f*)(preB + scb +  i   *sstep);
    #pragma unroll
    for (int i=0;i<8;i++) pnB[i] = *(const v2f*)(preB + scb + (i+8)*sstep);
    int lb = scb + 16*sstep;

    float hvA = 0.f, cstA = 0.f, hvB = 0.f, cstB = 0.f;
    float hbA[8], hbB[8];
    float* outA = out + (size_t)br*(BB*TT*24) + (size_t)bA*TT*24 + dir*12 + u
                + (size_t)(dir ? 223 : 0)*24;
    float* outB = outA + 2*(TT*24);

    for (int c=0;c<14;c++){
      STEPD(pcA[0],hvA,cstA,hbA,0) STEPD(pcB[0],hvB,cstB,hbB,0)
      STEPD(pcA[1],hvA,cstA,hbA,1) STEPD(pcB[1],hvB,cstB,hbB,1)
      STEPD(pcA[2],hvA,cstA,hbA,2) STEPD(pcB[2],hvB,cstB,hbB,2)
      STEPD(pcA[3],hvA,cstA,hbA,3) STEPD(pcB[3],hvB,cstB,hbB,3)
      STEPD(pcA[4],hvA,cstA,hbA,4) STEPD(pcB[4],hvB,cstB,hbB,4)
      STEPD(pcA[5],hvA,cstA,hbA,5) STEPD(pcB[5],hvB,cstB,hbB,5)
      STEPD(pcA[6],hvA,cstA,hbA,6) STEPD(pcB[6],hvB,cstB,hbB,6)
      STEPD(pcA[7],hvA,cstA,hbA,7) STEPD(pcB[7],hvB,cstB,hbB,7)
      FLUSHD(hbA, outA) FLUSHD(hbB, outB)
      if (c < 13){
        #pragma unroll
        for (int i=0;i<8;i++) pcA[i] = *(const v2f*)(preA + lb + i*sstep);
        #pragma unroll
        for (int i=0;i<8;i++) pcB[i] = *(const v2f*)(preB + lb + i*sstep);
        lb += 8*sstep;
      }
      STEPD(pnA[0],hvA,cstA,hbA,0) STEPD(pnB[0],hvB,cstB,hbB,0)
      STEPD(pnA[1],hvA,cstA,hbA,1) STEPD(pnB[1],hvB,cstB,hbB,1)
      STEPD(pnA[2],hvA,cstA,hbA,2) STEPD(pnB[2],hvB,cstB,hbB,2)
      STEPD(pnA[3],hvA,cstA,hbA,3) STEPD(pnB[3],hvB,cstB,hbB,3)
      STEPD(pnA[4],hvA,cstA,hbA,4) STEPD(pnB[4],hvB,cstB,hbB,4)
      STEPD(pnA[5],hvA,cstA,hbA,5) STEPD(pnB[5],hvB,cstB,hbB,5)
      STEPD(pnA[6],hvA,cstA,hbA,6) STEPD(pnB[6],hvB,cstB,hbB,6)
      STEPD(pnA[7],hvA,cstA,hbA,7) STEPD(pnB[7],hvB,cstB,hbB,7)
      FLUSHD(hbA, outA) FLUSHD(hbB, outB)
      if (c < 13){
        #pragma unroll
        for (int i=0;i<8;i++) pnA[i] = *(const v2f*)(preA + lb + i*sstep);
        #pragma unroll
        for (int i=0;i<8;i++) pnB[i] = *(const v2f*)(preB + lb + i*sstep);
        lb += 8*sstep;
      }
    }
  }
}

// ---------------- K6c: out[m][o] = (w1*o1+w2*o2) . Wc[o] + BC[o] ----------
__global__ void final_kernel(const float* __restrict__ o1, const float* __restrict__ o2,
    const float* __restrict__ Wc, const float* __restrict__ BC,
    const float* __restrict__ w1p, const float* __restrict__ w2p,
    float* __restrict__ out)
{
  int wid  = blockIdx.x*4 + (threadIdx.x>>6);
  int lane = threadIdx.x & 63;
  if (wid >= 128*9) return;
  int m = wid / 9, o = wid - m*9;
  float w1 = w1p[0], w2 = w2p[0];
  const float* r1 = o1 + (size_t)m*5376;
  const float* r2 = o2 + (size_t)m*5376;
  const float* wc = Wc + (size_t)o*5376;
  float acc = 0.f;
  for (int i=lane;i<5376;i+=64){
    acc += (w1*r1[i] + w2*r2[i]) * wc[i];
  }
  #pragma unroll
  for (int off=32;off;off>>=1) acc += __shfl_down(acc, off);
  if (lane==0) out[m*9+o] = acc + BC[o];
}

extern "C" void kernel_launch(void* const* d_in, const int* in_sizes, int n_in,
                              void* d_out, int out_size, void* d_ws, size_t ws_size,
                              hipStream_t stream) {
  (void)in_sizes; (void)n_in; (void)out_size; (void)ws_size;
  const float* x    = (const float*)d_in[0];
  const float* c1w1 = (const float*)d_in[1];
  const float* c1b1 = (const float*)d_in[2];
  const float* c1w2 = (const float*)d_in[3];
  const float* c1b2 = (const float*)d_in[4];
  const float* c2w1 = (const float*)d_in[5];
  const float* c2b1 = (const float*)d_in[6];
  const float* c2w2 = (const float*)d_in[7];
  const float* c2b2 = (const float*)d_in[8];
  const float* l10Wih = (const float*)d_in[9];
  const float* l10Whh = (const float*)d_in[10];
  const float* l10b   = (const float*)d_in[11];
  const float* l11Wih = (const float*)d_in[12];
  const float* l11Whh = (const float*)d_in[13];
  const float* l11b   = (const float*)d_in[14];
  const float* l20Wih = (const float*)d_in[15];
  const float* l20Whh = (const float*)d_in[16];
  const float* l20b   = (const float*)d_in[17];
  const float* l21Wih = (const float*)d_in[18];
  const float* l21Whh = (const float*)d_in[19];
  const float* l21b   = (const float*)d_in[20];
  const float* fcw1 = (const float*)d_in[21];
  const float* fcb1 = (const float*)d_in[22];
  const float* fcw2 = (const float*)d_in[23];
  const float* fcb2 = (const float*)d_in[24];
  const float* fcw3 = (const float*)d_in[25];
  const float* fcb3 = (const float*)d_in[26];
  const float* w1   = (const float*)d_in[27];
  const float* w2   = (const float*)d_in[28];
  float* out = (float*)d_out;

  float* ws  = (float*)d_ws;
  float* y    = ws;                       // 2 * 802816
  float* pre  = y   + 2*802816;           // 4 * 1376256
  float* ol0  = pre + 4*1376256;          // 2 * 688128
  float* ol1  = ol0 + 2*688128;           // 2 * 688128
  float* Wc   = ol1 + 2*688128;           // 48384
  float* BC   = Wc  + 48384;              // 9
  float* Wtb  = BC  + 9;                  // 9216
  float* wpart = ol1;                     // alias (see R9 note)

  conv_chain_kernel<<<14372,256,0,stream>>>(x, c1w1,c1b1,c1w2,c1b2, c2w1,c2b1,c2w2,c2b2, y,
      fcw3, fcw2, Wtb);
  pregate_fused_kernel<28,0><<<5713,256,0,stream>>>(y, 802816, l10Wih, l10b, l20Wih, l20b, pre,
      fcw1, fcw2, fcw3, fcb1, fcb2, fcb3, Wtb, wpart, Wc, BC);
  lstm_kernel<1><<<128,64,0,stream>>>(pre, l10Whh, l20Whh, ol0);
  pregate_fused_kernel<24,1><<<5565,256,0,stream>>>(ol0, 688128, l11Wih, l11b, l21Wih, l21b, pre,
      fcw1, fcw2, fcw3, fcb1, fcb2, fcb3, Wtb, wpart, Wc, BC);
  lstm_kernel<0><<<256,64,0,stream>>>(pre, l11Whh, l21Whh, ol1);
  final_kernel<<<288,256,0,stream>>>(ol1, ol1+688128, Wc, BC, w1, w2, out);
}

// Round 13
// 190.928 us; speedup vs baseline: 1.2030x; 1.2030x over previous
//
#include <hip/hip_runtime.h>

#define BB 128
#define TT 224
#define LL 224

typedef float v2f __attribute__((ext_vector_type(2)));

__device__ __forceinline__ float rcpf(float x){ return __builtin_amdgcn_rcpf(x); }

#if __has_builtin(__builtin_amdgcn_exp2f)
#define EXP2(x) __builtin_amdgcn_exp2f(x)
#else
#define EXP2(x) __expf((x)*0.6931471805599453f)
#endif

// DPP row rotate-right by N: dst[k] = src[(k-N)&15] within each 16-lane row
template<int N>
__device__ __forceinline__ float rorN(float x){
  int xi = __builtin_bit_cast(int, x);
  xi = __builtin_amdgcn_update_dpp(xi, xi, 0x120 + N, 0xf, 0xf, false);
  return __builtin_bit_cast(float, xi);
}

// v_permlane32_swap_b32: with a==b==x -> a'=low-half bcast, b'=high-half bcast
__device__ __forceinline__ void swap32(float& a, float& b){
  asm volatile("s_nop 1\n\tv_permlane32_swap_b32 %0, %1\n\ts_nop 1"
               : "+v"(a), "+v"(b));
}

// ---- K1: FUSED conv chain + layer-1 pre-gate + FC-composite blocks -------
// blocks [0,336): wpartA (inline Wt tile);  336: bcomp;
// blocks [337, 337+14336): conv 4 rows -> gates for both dirs of branch.
__global__ __launch_bounds__(256) void convpre_kernel(const float* __restrict__ x,
    const float* __restrict__ c1w1, const float* __restrict__ c1b1,
    const float* __restrict__ c1w2, const float* __restrict__ c1b2,
    const float* __restrict__ c2w1, const float* __restrict__ c2b1,
    const float* __restrict__ c2w2, const float* __restrict__ c2b2,
    const float* __restrict__ l10Wih, const float* __restrict__ l10b,
    const float* __restrict__ l20Wih, const float* __restrict__ l20b,
    float* __restrict__ pre,
    const float* __restrict__ fcw1, const float* __restrict__ fcw2,
    const float* __restrict__ fcw3, const float* __restrict__ fcb1,
    const float* __restrict__ fcb2, const float* __restrict__ fcb3,
    float* __restrict__ wpart, float* __restrict__ BC)
{
  __shared__ float sb[4112];
  int gb  = blockIdx.x;
  int tid = threadIdx.x;

  if (gb < 337){
    if (gb < 336){
      // wpartA: inline Wt tile (9x64 of fcw3@fcw2), then split-K over fcw1
      int s = gb / 21, jb = gb % 21;
      for (int i = tid; i < 576; i += 256){
        int o = i >> 6, n = i & 63;
        const float* f3 = fcw3 + o*192;
        const float* f2 = fcw2 + s*64 + n;
        float acc = 0.f;
        for (int p=0;p<192;p++) acc += f3[p]*f2[(size_t)p*1024];
        sb[i] = acc;
      }
      __syncthreads();
      int j = jb*256 + tid;
      float acc[9];
      #pragma unroll
      for (int o=0;o<9;o++) acc[o]=0.f;
      int nbase = s*64;
      #pragma unroll 4
      for (int n=0;n<64;n++){
        float v = fcw1[(size_t)(nbase+n)*5376 + j];
        #pragma unroll
        for (int o=0;o<9;o++) acc[o] += sb[o*64+n]*v;
      }
      #pragma unroll
      for (int o=0;o<9;o++) wpart[((size_t)s*9+o)*5376 + j] = acc[o];
    } else {
      // bcomp: BC[o] = fcb3[o] + fcw3[o,:] @ (fcb2 + fcw2@fcb1)
      if (tid < 192){
        const float* f2 = fcw2 + (size_t)tid*1024;
        float acc = 0.f;
        for (int n=0;n<1024;n++) acc += f2[n]*fcb1[n];
        sb[tid] = acc;
      }
      __syncthreads();
      if (tid < 9){
        float acc = fcb3[tid];
        const float* f3 = fcw3 + tid*192;
        for (int p=0;p<192;p++) acc += f3[p]*(fcb2[p]+sb[p]);
        BC[tid] = acc;
      }
    }
    return;
  }

  // -------- conv + pregate path --------
  float* xs   = sb;          // 896
  float* c1s  = sb + 896;    // 224
  float* y4   = sb + 1120;   // 112
  float* wihL = sb + 1232;   // 2*48*29 = 2784 (stride-29 padded)
  float* bL   = sb + 4016;   // 96

  int blk = gb - 337;                 // 0..14335
  int branch = (blk >= 7168);
  int lblk = branch ? blk - 7168 : blk;
  int b  = lblk / 56;
  int t0 = (lblk - b*56)*4;

  const float* w1 = branch ? c2w1 : c1w1;
  const float* w2 = branch ? c2w2 : c1w2;
  float b1  = branch ? c2b1[0] : c1b1[0];
  float b2v = branch ? c2b2[0] : c1b2[0];
  const float* wih = branch ? l20Wih : l10Wih;   // (2,48,28)
  const float* bia = branch ? l20b   : l10b;     // (2,48)

  // stage all LDS loads under one barrier
  if (tid < 224){
    *(float4*)&xs[tid*4] = *((const float4*)x + (size_t)blk*224 + tid);
  }
  for (int i = tid; i < 2688; i += 256){
    int d = (i >= 1344);
    int rem = i - d*1344;
    int row = rem / 28;
    int c = rem - row*28;
    wihL[d*1392 + row*29 + c] = wih[i];
  }
  if (tid < 96) bL[tid] = bia[tid];
  __syncthreads();

  if (tid < 224){
    int rr = tid / 56, cj = tid - rr*56;
    int base = 4*cj - 2;
    const float* xr = &xs[rr*224];
    float s = b1;
    #pragma unroll
    for (int kk=0;kk<8;kk++){
      int xi = base + kk;
      float xv = (xi>=0 && xi<224) ? xr[xi] : 0.f;
      s += xv * w1[kk];
    }
    c1s[rr*56 + cj] = fmaxf(s, 0.f);
  }
  __syncthreads();
  if (tid < 112){
    int rr = tid / 28, j = tid - rr*28;
    const float* cr = &c1s[rr*56];
    float o = b2v;
    #pragma unroll
    for (int pi=0;pi<3;pi++){
      int p = j - 1 + pi;
      float pool = 0.f;
      if (p>=0 && p<28){
        int i0 = 2*p - 1;
        float m = -1e30f;
        #pragma unroll
        for (int q=0;q<4;q++){
          int ii = i0+q;
          if (ii>=0 && ii<56) m = fmaxf(m, cr[ii]);
        }
        pool = fmaxf(m, 0.f);
      }
      o += pool * w2[pi];
    }
    y4[rr*28 + j] = fmaxf(o, 0.f);
  }
  __syncthreads();

  // pregate: 384 outputs = dirs(2) x rows(4) x gate-rows(48), row-major
  for (int oidx = tid; oidx < 384; oidx += 256){
    int d   = oidx / 192;
    int rem = oidx - d*192;
    int rr  = rem / 48;
    int row = rem - rr*48;             // Wih row 0..47 (i,f,g,o x 12)
    const float* wr = &wihL[d*1392 + row*29];
    const float* yr = &y4[rr*28];
    float acc = bL[d*48 + row];
    #pragma unroll
    for (int c=0;c<28;c++) acc += yr[c]*wr[c];
    // pre[run][b][t][48] with gate-pos = unit*4 + g  (g: 0=i 1=f 2=g 3=o)
    int unit = row % 12, g = row / 12;
    pre[(size_t)(2*branch + d)*(TT*BB*48) + ((size_t)b*224 + t0 + rr)*48
        + unit*4 + g] = acc;
  }
}

// -------- K2: layer-2 pre-gate GEMM (batch-major) + wpartB blocks --------
__global__ __launch_bounds__(256) void pregate2_kernel(
    const float* __restrict__ in,
    const float* __restrict__ wihA, const float* __restrict__ biasA,
    const float* __restrict__ wihB, const float* __restrict__ biasB,
    float* __restrict__ pre,
    const float* __restrict__ wpart, float* __restrict__ Wc)
{
  const int D = 24;
  __shared__ float sb[48*24 + 48];
  int gb  = blockIdx.x;
  int tid = threadIdx.x;

  if (gb < 189){
    int idx = gb*256 + tid;   // 189*256 = 48384 exactly
    float a = 0.f;
    #pragma unroll
    for (int s=0;s<16;s++) a += wpart[(size_t)s*48384 + idx];
    Wc[idx] = a;
    return;
  }

  int pgb = gb - 189;
  float* wL = sb;
  float* bL = sb + 48*D;
  int r = pgb / 1344;
  int lin = (pgb % 1344)*256 + tid;
  int br = r>>1, dir = r&1;
  const float* wih  = (br ? wihB  : wihA)  + dir*48*D;
  const float* bias = (br ? biasB : biasA) + dir*48;
  for (int i = tid; i < 48*D; i += 256) wL[i]=wih[i];
  if (tid < 48) bL[tid]=bias[tid];
  __syncthreads();
  int tb = lin/12;  int k = lin - tb*12;   // tb = b*224 + t (batch-major)
  const float* rowp = in + (size_t)br*688128 + (size_t)tb*D;
  float aI=bL[k], aF=bL[12+k], aG=bL[24+k], aO=bL[36+k];
  const float4* rp4 = (const float4*)rowp;
  #pragma unroll
  for (int d4=0; d4<D/4; d4++){
    float4 xv = rp4[d4];
    float4 wI = *(const float4*)&wL[(0*12+k)*D + d4*4];
    float4 wF = *(const float4*)&wL[(1*12+k)*D + d4*4];
    float4 wG = *(const float4*)&wL[(2*12+k)*D + d4*4];
    float4 wO = *(const float4*)&wL[(3*12+k)*D + d4*4];
    aI += xv.x*wI.x + xv.y*wI.y + xv.z*wI.z + xv.w*wI.w;
    aF += xv.x*wF.x + xv.y*wF.y + xv.z*wF.z + xv.w*wF.w;
    aG += xv.x*wG.x + xv.y*wG.y + xv.z*wG.z + xv.w*wG.w;
    aO += xv.x*wO.x + xv.y*wO.y + xv.z*wO.z + xv.w*wO.w;
  }
  float4* o = (float4*)(pre + (size_t)r*(TT*BB*48) + (size_t)tb*48 + k*4);
  *o = make_float4(aI,aF,aG,aO);
}

// ---------------- K3: LSTM scan, single-chain (R11 form) ------------------
#define LSTM_STEP(P, SS) { \
  float x1=rorN<1>(hv), x2=rorN<2>(hv), x3=rorN<3>(hv), x4=rorN<4>(hv), \
        x5=rorN<5>(hv), x6=rorN<6>(hv), x7=rorN<7>(hv), x8=rorN<8>(hv), \
        x9=rorN<9>(hv), x10=rorN<10>(hv), x11=rorN<11>(hv), x12=rorN<12>(hv), \
        x13=rorN<13>(hv), x14=rorN<14>(hv), x15=rorN<15>(hv); \
  v2f a0 = (P); \
  a0 += w[0]*(v2f){hv,hv};   a0 += w[1]*(v2f){x1,x1};   a0 += w[2]*(v2f){x2,x2};   a0 += w[3]*(v2f){x3,x3}; \
  v2f a1 = w[4]*(v2f){x4,x4};   a1 += w[5]*(v2f){x5,x5};   a1 += w[6]*(v2f){x6,x6};   a1 += w[7]*(v2f){x7,x7}; \
  v2f a2 = w[8]*(v2f){x8,x8};   a2 += w[9]*(v2f){x9,x9};   a2 += w[10]*(v2f){x10,x10}; a2 += w[11]*(v2f){x11,x11}; \
  v2f a3 = w[12]*(v2f){x12,x12}; a3 += w[13]*(v2f){x13,x13}; a3 += w[14]*(v2f){x14,x14}; a3 += w[15]*(v2f){x15,x15}; \
  v2f gg = (a0+a1)+(a2+a3); \
  v2f m  = gg*kmul; \
  v2f e  = { EXP2(m.x), EXP2(m.y) }; \
  e += (v2f){1.f,1.f}; \
  v2f d  = { rcpf(e.x), rcpf(e.y) }; \
  v2f res = ca*d + cb; \
  float p0 = res.x, p1 = res.x; swap32(p0, p1); \
  float q0 = res.y, q1 = res.y; swap32(q0, q1); \
  cst = fmaf(q0, cst, p0*p1); \
  float et = EXP2(cst*2.885390082f); \
  float dt = rcpf(et+1.f); \
  hv = q1*fmaf(-2.f, dt, 1.f); \
  hbuf[SS] = hv; }

#define FLUSH8 { \
  if (doSt){ \
    _Pragma("unroll") \
    for (int q=0;q<8;q++) outP[q*ostep] = hbuf[q]; \
  } \
  outP += 8*ostep; }

__global__ __launch_bounds__(64) __attribute__((amdgpu_waves_per_eu(1,1)))
void lstm_kernel(const float* __restrict__ pre,
    const float* __restrict__ whhA, const float* __restrict__ whhB,
    float* __restrict__ out)
{
  int blk  = blockIdx.x;
  int r    = blk >> 6;            // run 0..3 (64 blocks per run)
  int br   = r >> 1, dir = r & 1;
  int lane = threadIdx.x;
  int u    = lane & 15;
  int bh   = (lane >> 4) & 1;
  int rbit = lane >> 5;
  int keff = (u < 12) ? u : 11;
  int b    = (blk & 63)*2 + bh;
  const float* whh = (br ? whhB : whhA) + dir*48*12;

  v2f w[16];
  #pragma unroll
  for (int rr=0; rr<16; rr++){
    int j = (u - rr) & 15;
    bool vld = (j < 12) && (u < 12);
    int uw = (u < 12) ? u : 0;
    int jw = (j < 12) ? j : 0;
    float wa = whh[((rbit?24:0)  + uw)*12 + jw];
    float wb = whh[((rbit?36:12) + uw)*12 + jw];
    w[rr] = (v2f){ vld ? wa : 0.f, vld ? wb : 0.f };
  }
  const v2f kmul = rbit ? (v2f){2.885390082f, -1.442695041f}
                        : (v2f){-1.442695041f, -1.442695041f};
  const v2f ca   = rbit ? (v2f){-2.f, 1.f} : (v2f){1.f, 1.f};
  const v2f cb   = rbit ? (v2f){ 1.f, 0.f} : (v2f){0.f, 0.f};

  const float* preR = pre + (size_t)r*(TT*BB*48) + (size_t)b*(TT*48) + keff*4 + rbit*2;
  const int sstep = dir ? -48 : 48;
  int scb = dir ? 223*48 : 0;

  v2f pcur[8], pnext[8];
  #pragma unroll
  for (int i=0;i<8;i++) pcur[i]  = *(const v2f*)(preR + scb +  i   *sstep);
  #pragma unroll
  for (int i=0;i<8;i++) pnext[i] = *(const v2f*)(preR + scb + (i+8)*sstep);
  int lb = scb + 16*sstep;

  float hv = 0.f, cst = 0.f;
  float hbuf[8];
  const int ostep = dir ? -24 : 24;
  float* outP = out + (size_t)br*(BB*TT*24) + (size_t)b*TT*24 + dir*12 + u
              + (size_t)(dir ? 223 : 0)*24;
  const bool doSt = (rbit==0) && (u < 12);

  for (int c=0;c<14;c++){
    LSTM_STEP(pcur[0],0) LSTM_STEP(pcur[1],1) LSTM_STEP(pcur[2],2) LSTM_STEP(pcur[3],3)
    LSTM_STEP(pcur[4],4) LSTM_STEP(pcur[5],5) LSTM_STEP(pcur[6],6) LSTM_STEP(pcur[7],7)
    FLUSH8
    if (c < 13){
      #pragma unroll
      for (int i=0;i<8;i++) pcur[i] = *(const v2f*)(preR + lb + i*sstep);
      lb += 8*sstep;
    }
    LSTM_STEP(pnext[0],0) LSTM_STEP(pnext[1],1) LSTM_STEP(pnext[2],2) LSTM_STEP(pnext[3],3)
    LSTM_STEP(pnext[4],4) LSTM_STEP(pnext[5],5) LSTM_STEP(pnext[6],6) LSTM_STEP(pnext[7],7)
    FLUSH8
    if (c < 13){
      #pragma unroll
      for (int i=0;i<8;i++) pnext[i] = *(const v2f*)(preR + lb + i*sstep);
      lb += 8*sstep;
    }
  }
}

// ---------------- K6c: out[m][o] = (w1*o1+w2*o2) . Wc[o] + BC[o] ----------
__global__ void final_kernel(const float* __restrict__ o1, const float* __restrict__ o2,
    const float* __restrict__ Wc, const float* __restrict__ BC,
    const float* __restrict__ w1p, const float* __restrict__ w2p,
    float* __restrict__ out)
{
  int wid  = blockIdx.x*4 + (threadIdx.x>>6);
  int lane = threadIdx.x & 63;
  if (wid >= 128*9) return;
  int m = wid / 9, o = wid - m*9;
  float w1 = w1p[0], w2 = w2p[0];
  const float* r1 = o1 + (size_t)m*5376;
  const float* r2 = o2 + (size_t)m*5376;
  const float* wc = Wc + (size_t)o*5376;
  float acc = 0.f;
  for (int i=lane;i<5376;i+=64){
    acc += (w1*r1[i] + w2*r2[i]) * wc[i];
  }
  #pragma unroll
  for (int off=32;off;off>>=1) acc += __shfl_down(acc, off);
  if (lane==0) out[m*9+o] = acc + BC[o];
}

extern "C" void kernel_launch(void* const* d_in, const int* in_sizes, int n_in,
                              void* d_out, int out_size, void* d_ws, size_t ws_size,
                              hipStream_t stream) {
  (void)in_sizes; (void)n_in; (void)out_size; (void)ws_size;
  const float* x    = (const float*)d_in[0];
  const float* c1w1 = (const float*)d_in[1];
  const float* c1b1 = (const float*)d_in[2];
  const float* c1w2 = (const float*)d_in[3];
  const float* c1b2 = (const float*)d_in[4];
  const float* c2w1 = (const float*)d_in[5];
  const float* c2b1 = (const float*)d_in[6];
  const float* c2w2 = (const float*)d_in[7];
  const float* c2b2 = (const float*)d_in[8];
  const float* l10Wih = (const float*)d_in[9];
  const float* l10Whh = (const float*)d_in[10];
  const float* l10b   = (const float*)d_in[11];
  const float* l11Wih = (const float*)d_in[12];
  const float* l11Whh = (const float*)d_in[13];
  const float* l11b   = (const float*)d_in[14];
  const float* l20Wih = (const float*)d_in[15];
  const float* l20Whh = (const float*)d_in[16];
  const float* l20b   = (const float*)d_in[17];
  const float* l21Wih = (const float*)d_in[18];
  const float* l21Whh = (const float*)d_in[19];
  const float* l21b   = (const float*)d_in[20];
  const float* fcw1 = (const float*)d_in[21];
  const float* fcb1 = (const float*)d_in[22];
  const float* fcw2 = (const float*)d_in[23];
  const float* fcb2 = (const float*)d_in[24];
  const float* fcw3 = (const float*)d_in[25];
  const float* fcb3 = (const float*)d_in[26];
  const float* w1   = (const float*)d_in[27];
  const float* w2   = (const float*)d_in[28];
  float* out = (float*)d_out;

  float* ws  = (float*)d_ws;
  float* wpart = ws;                      // 774144 (region formerly 'y')
  float* pre  = ws  + 2*802816;           // 4 * 1376256
  float* ol0  = pre + 4*1376256;          // 2 * 688128
  float* ol1  = ol0 + 2*688128;           // 2 * 688128
  float* Wc   = ol1 + 2*688128;           // 48384
  float* BC   = Wc  + 48384;              // 9

  convpre_kernel<<<14673,256,0,stream>>>(x, c1w1,c1b1,c1w2,c1b2, c2w1,c2b1,c2w2,c2b2,
      l10Wih, l10b, l20Wih, l20b, pre,
      fcw1, fcw2, fcw3, fcb1, fcb2, fcb3, wpart, BC);
  lstm_kernel<<<256,64,0,stream>>>(pre, l10Whh, l20Whh, ol0);
  pregate2_kernel<<<5565,256,0,stream>>>(ol0, l11Wih, l11b, l21Wih, l21b, pre, wpart, Wc);
  lstm_kernel<<<256,64,0,stream>>>(pre, l11Whh, l21Whh, ol1);
  final_kernel<<<288,256,0,stream>>>(ol1, ol1+688128, Wc, BC, w1, w2, out);
}

// Round 14
// 190.174 us; speedup vs baseline: 1.2078x; 1.0040x over previous
//
#include <hip/hip_runtime.h>

#define BB 128
#define TT 224
#define LL 224

typedef float v2f __attribute__((ext_vector_type(2)));

__device__ __forceinline__ float rcpf(float x){ return __builtin_amdgcn_rcpf(x); }

#if __has_builtin(__builtin_amdgcn_exp2f)
#define EXP2(x) __builtin_amdgcn_exp2f(x)
#else
#define EXP2(x) __expf((x)*0.6931471805599453f)
#endif

// DPP row rotate-right by N: dst[k] = src[(k-N)&15] within each 16-lane row
template<int N>
__device__ __forceinline__ float rorN(float x){
  int xi = __builtin_bit_cast(int, x);
  xi = __builtin_amdgcn_update_dpp(xi, xi, 0x120 + N, 0xf, 0xf, false);
  return __builtin_bit_cast(float, xi);
}

// v_permlane32_swap_b32: with a==b==x -> a'=low-half bcast, b'=high-half bcast
__device__ __forceinline__ void swap32(float& a, float& b){
  asm volatile("s_nop 1\n\tv_permlane32_swap_b32 %0, %1\n\ts_nop 1"
               : "+v"(a), "+v"(b));
}

// ---- K1: FUSED conv chain + layer-1 pre-gate + FC-composite blocks -------
// blocks [0,336): wpartA (inline Wt tile);  336: bcomp;
// blocks [337, 337+3584): conv 16 rows -> gates for both dirs of branch.
// LDS layout (floats): xs4[4][16][57] phase-split x (conflict-free conv taps),
// c1s[16][57], y4[16][29], wihL[96][29], bL[96].
__global__ __launch_bounds__(256) void convpre_kernel(const float* __restrict__ x,
    const float* __restrict__ c1w1, const float* __restrict__ c1b1,
    const float* __restrict__ c1w2, const float* __restrict__ c1b2,
    const float* __restrict__ c2w1, const float* __restrict__ c2b1,
    const float* __restrict__ c2w2, const float* __restrict__ c2b2,
    const float* __restrict__ l10Wih, const float* __restrict__ l10b,
    const float* __restrict__ l20Wih, const float* __restrict__ l20b,
    float* __restrict__ pre,
    const float* __restrict__ fcw1, const float* __restrict__ fcw2,
    const float* __restrict__ fcw3, const float* __restrict__ fcb1,
    const float* __restrict__ fcb2, const float* __restrict__ fcb3,
    float* __restrict__ wpart, float* __restrict__ BC)
{
  __shared__ float sb[7904];
  int gb  = blockIdx.x;
  int tid = threadIdx.x;

  if (gb < 337){
    if (gb < 336){
      // wpartA: inline Wt tile (9x64 of fcw3@fcw2), then split-K over fcw1
      int s = gb / 21, jb = gb % 21;
      for (int i = tid; i < 576; i += 256){
        int o = i >> 6, n = i & 63;
        const float* f3 = fcw3 + o*192;
        const float* f2 = fcw2 + s*64 + n;
        float acc = 0.f;
        for (int p=0;p<192;p++) acc += f3[p]*f2[(size_t)p*1024];
        sb[i] = acc;
      }
      __syncthreads();
      int j = jb*256 + tid;
      float acc[9];
      #pragma unroll
      for (int o=0;o<9;o++) acc[o]=0.f;
      int nbase = s*64;
      #pragma unroll 4
      for (int n=0;n<64;n++){
        float v = fcw1[(size_t)(nbase+n)*5376 + j];
        #pragma unroll
        for (int o=0;o<9;o++) acc[o] += sb[o*64+n]*v;
      }
      #pragma unroll
      for (int o=0;o<9;o++) wpart[((size_t)s*9+o)*5376 + j] = acc[o];
    } else {
      // bcomp: BC[o] = fcb3[o] + fcw3[o,:] @ (fcb2 + fcw2@fcb1)
      if (tid < 192){
        const float* f2 = fcw2 + (size_t)tid*1024;
        float acc = 0.f;
        for (int n=0;n<1024;n++) acc += f2[n]*fcb1[n];
        sb[tid] = acc;
      }
      __syncthreads();
      if (tid < 9){
        float acc = fcb3[tid];
        const float* f3 = fcw3 + tid*192;
        for (int p=0;p<192;p++) acc += f3[p]*(fcb2[p]+sb[p]);
        BC[tid] = acc;
      }
    }
    return;
  }

  // -------- conv + pregate path: 16 rows per block --------
  float* xs4  = sb;          // [p][row][c] : p*912 + row*57 + c
  float* c1s  = sb + 3648;   // row*57 + cj
  float* y4   = sb + 4560;   // row*29 + j
  float* wihL = sb + 5024;   // (d*48+row)*29 + c
  float* bL   = sb + 7808;   // 96

  int blk = gb - 337;                 // 0..3583
  int branch = (blk >= 1792);
  int lblk = blk - branch*1792;
  int b  = lblk / 14;
  int t0 = (lblk - b*14)*16;
  size_t rbase = ((size_t)(branch*128 + b))*224 + t0;   // global x row
  size_t prow  = (size_t)b*224 + t0;                    // pre row within run

  const float* w1 = branch ? c2w1 : c1w1;
  const float* w2 = branch ? c2w2 : c1w2;
  float b1  = branch ? c2b1[0] : c1b1[0];
  float b2v = branch ? c2b2[0] : c1b2[0];
  const float* wih = branch ? l20Wih : l10Wih;   // (2,48,28)
  const float* bia = branch ? l20b   : l10b;     // (2,48)

  // stage x (896 float4 -> phase-split), weights, biases
  for (int i = tid; i < 896; i += 256){
    int row = i / 56, c = i - row*56;
    float4 v = *((const float4*)x + (rbase + row)*56 + c);
    int o = row*57 + c;
    xs4[o]          = v.x;
    xs4[912  + o]   = v.y;
    xs4[1824 + o]   = v.z;
    xs4[2736 + o]   = v.w;
  }
  for (int i = tid; i < 3072; i += 256){
    int row = i >> 5, c = i & 31;
    if (c < 28) wihL[row*29 + c] = wih[row*28 + c];
  }
  if (tid < 96) bL[tid] = bia[tid];
  __syncthreads();

  float w1r[8];
  #pragma unroll
  for (int kk=0;kk<8;kk++) w1r[kk]=w1[kk];

  // conv1 stride-4 pad-2 + relu: all LDS reads stride-1 across lanes
  for (int i = tid; i < 896; i += 256){
    int row = i / 56, cj = i - row*56;
    const float* xp = &xs4[row*57 + cj];
    float s = b1;
    if (cj >= 1){
      s += w1r[0]*xp[1824 - 1];
      s += w1r[1]*xp[2736 - 1];
    }
    s += w1r[2]*xp[0];
    s += w1r[3]*xp[912];
    s += w1r[4]*xp[1824];
    s += w1r[5]*xp[2736];
    if (cj <= 54){
      s += w1r[6]*xp[1];
      s += w1r[7]*xp[912 + 1];
    }
    c1s[row*57 + cj] = fmaxf(s, 0.f);
  }
  __syncthreads();

  // maxpool(4,2,pad1) + relu + conv3(pad1) + relu
  for (int i = tid; i < 448; i += 256){
    int row = i / 28, j = i - row*28;
    const float* cr = &c1s[row*57];
    float o = b2v;
    #pragma unroll
    for (int pi=0;pi<3;pi++){
      int p = j - 1 + pi;
      float pool = 0.f;
      if (p>=0 && p<28){
        int i0 = 2*p - 1;
        float m = -1e30f;
        #pragma unroll
        for (int q=0;q<4;q++){
          int ii = i0+q;
          if (ii>=0 && ii<56) m = fmaxf(m, cr[ii]);
        }
        pool = fmaxf(m, 0.f);
      }
      o += pool * w2[pi];
    }
    y4[row*29 + j] = fmaxf(o, 0.f);
  }
  __syncthreads();

  // pregate: 1536 outputs = dirs(2) x rows(16) x gate-rows(48)
  for (int i = tid; i < 1536; i += 256){
    int d   = i / 768;
    int rem = i - d*768;
    int rr  = rem / 48;
    int row = rem - rr*48;
    const float* wr = &wihL[(d*48 + row)*29];
    const float* yr = &y4[rr*29];
    float acc = bL[d*48 + row];
    #pragma unroll
    for (int c=0;c<28;c++) acc += yr[c]*wr[c];
    int unit = row % 12, g = row / 12;
    pre[(size_t)(2*branch + d)*(TT*BB*48) + (prow + rr)*48 + unit*4 + g] = acc;
  }
}

// -------- K2: layer-2 pre-gate GEMM (batch-major) + wpartB blocks --------
__global__ __launch_bounds__(256) void pregate2_kernel(
    const float* __restrict__ in,
    const float* __restrict__ wihA, const float* __restrict__ biasA,
    const float* __restrict__ wihB, const float* __restrict__ biasB,
    float* __restrict__ pre,
    const float* __restrict__ wpart, float* __restrict__ Wc)
{
  const int D = 24;
  __shared__ float sb[48*24 + 48];
  int gb  = blockIdx.x;
  int tid = threadIdx.x;

  if (gb < 189){
    int idx = gb*256 + tid;   // 189*256 = 48384 exactly
    float a = 0.f;
    #pragma unroll
    for (int s=0;s<16;s++) a += wpart[(size_t)s*48384 + idx];
    Wc[idx] = a;
    return;
  }

  int pgb = gb - 189;
  float* wL = sb;
  float* bL = sb + 48*D;
  int r = pgb / 1344;
  int lin = (pgb % 1344)*256 + tid;
  int br = r>>1, dir = r&1;
  const float* wih  = (br ? wihB  : wihA)  + dir*48*D;
  const float* bias = (br ? biasB : biasA) + dir*48;
  for (int i = tid; i < 48*D; i += 256) wL[i]=wih[i];
  if (tid < 48) bL[tid]=bias[tid];
  __syncthreads();
  int tb = lin/12;  int k = lin - tb*12;   // tb = b*224 + t (batch-major)
  const float* rowp = in + (size_t)br*688128 + (size_t)tb*D;
  float aI=bL[k], aF=bL[12+k], aG=bL[24+k], aO=bL[36+k];
  const float4* rp4 = (const float4*)rowp;
  #pragma unroll
  for (int d4=0; d4<D/4; d4++){
    float4 xv = rp4[d4];
    float4 wI = *(const float4*)&wL[(0*12+k)*D + d4*4];
    float4 wF = *(const float4*)&wL[(1*12+k)*D + d4*4];
    float4 wG = *(const float4*)&wL[(2*12+k)*D + d4*4];
    float4 wO = *(const float4*)&wL[(3*12+k)*D + d4*4];
    aI += xv.x*wI.x + xv.y*wI.y + xv.z*wI.z + xv.w*wI.w;
    aF += xv.x*wF.x + xv.y*wF.y + xv.z*wF.z + xv.w*wF.w;
    aG += xv.x*wG.x + xv.y*wG.y + xv.z*wG.z + xv.w*wG.w;
    aO += xv.x*wO.x + xv.y*wO.y + xv.z*wO.z + xv.w*wO.w;
  }
  float4* o = (float4*)(pre + (size_t)r*(TT*BB*48) + (size_t)tb*48 + k*4);
  *o = make_float4(aI,aF,aG,aO);
}

// ---------------- K3: LSTM scan, single-chain (R11 form) ------------------
#define LSTM_STEP(P, SS) { \
  float x1=rorN<1>(hv), x2=rorN<2>(hv), x3=rorN<3>(hv), x4=rorN<4>(hv), \
        x5=rorN<5>(hv), x6=rorN<6>(hv), x7=rorN<7>(hv), x8=rorN<8>(hv), \
        x9=rorN<9>(hv), x10=rorN<10>(hv), x11=rorN<11>(hv), x12=rorN<12>(hv), \
        x13=rorN<13>(hv), x14=rorN<14>(hv), x15=rorN<15>(hv); \
  v2f a0 = (P); \
  a0 += w[0]*(v2f){hv,hv};   a0 += w[1]*(v2f){x1,x1};   a0 += w[2]*(v2f){x2,x2};   a0 += w[3]*(v2f){x3,x3}; \
  v2f a1 = w[4]*(v2f){x4,x4};   a1 += w[5]*(v2f){x5,x5};   a1 += w[6]*(v2f){x6,x6};   a1 += w[7]*(v2f){x7,x7}; \
  v2f a2 = w[8]*(v2f){x8,x8};   a2 += w[9]*(v2f){x9,x9};   a2 += w[10]*(v2f){x10,x10}; a2 += w[11]*(v2f){x11,x11}; \
  v2f a3 = w[12]*(v2f){x12,x12}; a3 += w[13]*(v2f){x13,x13}; a3 += w[14]*(v2f){x14,x14}; a3 += w[15]*(v2f){x15,x15}; \
  v2f gg = (a0+a1)+(a2+a3); \
  v2f m  = gg*kmul; \
  v2f e  = { EXP2(m.x), EXP2(m.y) }; \
  e += (v2f){1.f,1.f}; \
  v2f d  = { rcpf(e.x), rcpf(e.y) }; \
  v2f res = ca*d + cb; \
  float p0 = res.x, p1 = res.x; swap32(p0, p1); \
  float q0 = res.y, q1 = res.y; swap32(q0, q1); \
  cst = fmaf(q0, cst, p0*p1); \
  float et = EXP2(cst*2.885390082f); \
  float dt = rcpf(et+1.f); \
  hv = q1*fmaf(-2.f, dt, 1.f); \
  hbuf[SS] = hv; }

#define FLUSH8 { \
  if (doSt){ \
    _Pragma("unroll") \
    for (int q=0;q<8;q++) outP[q*ostep] = hbuf[q]; \
  } \
  outP += 8*ostep; }

__global__ __launch_bounds__(64) __attribute__((amdgpu_waves_per_eu(1,1)))
void lstm_kernel(const float* __restrict__ pre,
    const float* __restrict__ whhA, const float* __restrict__ whhB,
    float* __restrict__ out)
{
  int blk  = blockIdx.x;
  int r    = blk >> 6;            // run 0..3 (64 blocks per run)
  int br   = r >> 1, dir = r & 1;
  int lane = threadIdx.x;
  int u    = lane & 15;
  int bh   = (lane >> 4) & 1;
  int rbit = lane >> 5;
  int keff = (u < 12) ? u : 11;
  int b    = (blk & 63)*2 + bh;
  const float* whh = (br ? whhB : whhA) + dir*48*12;

  v2f w[16];
  #pragma unroll
  for (int rr=0; rr<16; rr++){
    int j = (u - rr) & 15;
    bool vld = (j < 12) && (u < 12);
    int uw = (u < 12) ? u : 0;
    int jw = (j < 12) ? j : 0;
    float wa = whh[((rbit?24:0)  + uw)*12 + jw];
    float wb = whh[((rbit?36:12) + uw)*12 + jw];
    w[rr] = (v2f){ vld ? wa : 0.f, vld ? wb : 0.f };
  }
  const v2f kmul = rbit ? (v2f){2.885390082f, -1.442695041f}
                        : (v2f){-1.442695041f, -1.442695041f};
  const v2f ca   = rbit ? (v2f){-2.f, 1.f} : (v2f){1.f, 1.f};
  const v2f cb   = rbit ? (v2f){ 1.f, 0.f} : (v2f){0.f, 0.f};

  const float* preR = pre + (size_t)r*(TT*BB*48) + (size_t)b*(TT*48) + keff*4 + rbit*2;
  const int sstep = dir ? -48 : 48;
  int scb = dir ? 223*48 : 0;

  v2f pcur[8], pnext[8];
  #pragma unroll
  for (int i=0;i<8;i++) pcur[i]  = *(const v2f*)(preR + scb +  i   *sstep);
  #pragma unroll
  for (int i=0;i<8;i++) pnext[i] = *(const v2f*)(preR + scb + (i+8)*sstep);
  int lb = scb + 16*sstep;

  float hv = 0.f, cst = 0.f;
  float hbuf[8];
  const int ostep = dir ? -24 : 24;
  float* outP = out + (size_t)br*(BB*TT*24) + (size_t)b*TT*24 + dir*12 + u
              + (size_t)(dir ? 223 : 0)*24;
  const bool doSt = (rbit==0) && (u < 12);

  for (int c=0;c<14;c++){
    LSTM_STEP(pcur[0],0) LSTM_STEP(pcur[1],1) LSTM_STEP(pcur[2],2) LSTM_STEP(pcur[3],3)
    LSTM_STEP(pcur[4],4) LSTM_STEP(pcur[5],5) LSTM_STEP(pcur[6],6) LSTM_STEP(pcur[7],7)
    FLUSH8
    if (c < 13){
      #pragma unroll
      for (int i=0;i<8;i++) pcur[i] = *(const v2f*)(preR + lb + i*sstep);
      lb += 8*sstep;
    }
    LSTM_STEP(pnext[0],0) LSTM_STEP(pnext[1],1) LSTM_STEP(pnext[2],2) LSTM_STEP(pnext[3],3)
    LSTM_STEP(pnext[4],4) LSTM_STEP(pnext[5],5) LSTM_STEP(pnext[6],6) LSTM_STEP(pnext[7],7)
    FLUSH8
    if (c < 13){
      #pragma unroll
      for (int i=0;i<8;i++) pnext[i] = *(const v2f*)(preR + lb + i*sstep);
      lb += 8*sstep;
    }
  }
}

// ---------------- K6c: out[m][o] = (w1*o1+w2*o2) . Wc[o] + BC[o] ----------
__global__ void final_kernel(const float* __restrict__ o1, const float* __restrict__ o2,
    const float* __restrict__ Wc, const float* __restrict__ BC,
    const float* __restrict__ w1p, const float* __restrict__ w2p,
    float* __restrict__ out)
{
  int wid  = blockIdx.x*4 + (threadIdx.x>>6);
  int lane = threadIdx.x & 63;
  if (wid >= 128*9) return;
  int m = wid / 9, o = wid - m*9;
  float w1 = w1p[0], w2 = w2p[0];
  const float* r1 = o1 + (size_t)m*5376;
  const float* r2 = o2 + (size_t)m*5376;
  const float* wc = Wc + (size_t)o*5376;
  float acc = 0.f;
  for (int i=lane;i<5376;i+=64){
    acc += (w1*r1[i] + w2*r2[i]) * wc[i];
  }
  #pragma unroll
  for (int off=32;off;off>>=1) acc += __shfl_down(acc, off);
  if (lane==0) out[m*9+o] = acc + BC[o];
}

extern "C" void kernel_launch(void* const* d_in, const int* in_sizes, int n_in,
                              void* d_out, int out_size, void* d_ws, size_t ws_size,
                              hipStream_t stream) {
  (void)in_sizes; (void)n_in; (void)out_size; (void)ws_size;
  const float* x    = (const float*)d_in[0];
  const float* c1w1 = (const float*)d_in[1];
  const float* c1b1 = (const float*)d_in[2];
  const float* c1w2 = (const float*)d_in[3];
  const float* c1b2 = (const float*)d_in[4];
  const float* c2w1 = (const float*)d_in[5];
  const float* c2b1 = (const float*)d_in[6];
  const float* c2w2 = (const float*)d_in[7];
  const float* c2b2 = (const float*)d_in[8];
  const float* l10Wih = (const float*)d_in[9];
  const float* l10Whh = (const float*)d_in[10];
  const float* l10b   = (const float*)d_in[11];
  const float* l11Wih = (const float*)d_in[12];
  const float* l11Whh = (const float*)d_in[13];
  const float* l11b   = (const float*)d_in[14];
  const float* l20Wih = (const float*)d_in[15];
  const float* l20Whh = (const float*)d_in[16];
  const float* l20b   = (const float*)d_in[17];
  const float* l21Wih = (const float*)d_in[18];
  const float* l21Whh = (const float*)d_in[19];
  const float* l21b   = (const float*)d_in[20];
  const float* fcw1 = (const float*)d_in[21];
  const float* fcb1 = (const float*)d_in[22];
  const float* fcw2 = (const float*)d_in[23];
  const float* fcb2 = (const float*)d_in[24];
  const float* fcw3 = (const float*)d_in[25];
  const float* fcb3 = (const float*)d_in[26];
  const float* w1   = (const float*)d_in[27];
  const float* w2   = (const float*)d_in[28];
  float* out = (float*)d_out;

  float* ws  = (float*)d_ws;
  float* wpart = ws;                      // 774144 (region formerly 'y')
  float* pre  = ws  + 2*802816;           // 4 * 1376256
  float* ol0  = pre + 4*1376256;          // 2 * 688128
  float* ol1  = ol0 + 2*688128;           // 2 * 688128
  float* Wc   = ol1 + 2*688128;           // 48384
  float* BC   = Wc  + 48384;              // 9

  convpre_kernel<<<3921,256,0,stream>>>(x, c1w1,c1b1,c1w2,c1b2, c2w1,c2b1,c2w2,c2b2,
      l10Wih, l10b, l20Wih, l20b, pre,
      fcw1, fcw2, fcw3, fcb1, fcb2, fcb3, wpart, BC);
  lstm_kernel<<<256,64,0,stream>>>(pre, l10Whh, l20Whh, ol0);
  pregate2_kernel<<<5565,256,0,stream>>>(ol0, l11Wih, l11b, l21Wih, l21b, pre, wpart, Wc);
  lstm_kernel<<<256,64,0,stream>>>(pre, l11Whh, l21Whh, ol1);
  final_kernel<<<288,256,0,stream>>>(ol1, ol1+688128, Wc, BC, w1, w2, out);
}

// Round 15
// 182.070 us; speedup vs baseline: 1.2616x; 1.0445x over previous
//
#include <hip/hip_runtime.h>

#define BB 128
#define TT 224
#define LL 224

typedef float v2f __attribute__((ext_vector_type(2)));

__device__ __forceinline__ float rcpf(float x){ return __builtin_amdgcn_rcpf(x); }

#if __has_builtin(__builtin_amdgcn_exp2f)
#define EXP2(x) __builtin_amdgcn_exp2f(x)
#else
#define EXP2(x) __expf((x)*0.6931471805599453f)
#endif

// DPP row rotate-right by N: dst[k] = src[(k-N)&15] within each 16-lane row
template<int N>
__device__ __forceinline__ float rorN(float x){
  int xi = __builtin_bit_cast(int, x);
  xi = __builtin_amdgcn_update_dpp(xi, xi, 0x120 + N, 0xf, 0xf, false);
  return __builtin_bit_cast(float, xi);
}

// v_permlane32_swap_b32: with a==b==x -> a'=low-half bcast, b'=high-half bcast
__device__ __forceinline__ void swap32(float& a, float& b){
  asm volatile("s_nop 1\n\tv_permlane32_swap_b32 %0, %1\n\ts_nop 1"
               : "+v"(a), "+v"(b));
}

// ---- K1: FUSED conv chain + layer-1 pre-gate + FC-composite blocks -------
// blocks [0,336): wpartA (inline Wt tile);  336: bcomp;
// blocks [337, 337+3584): conv 16 rows -> gates for both dirs of branch.
// LDS (floats): xs4[4][16][57] phase-split x, c1s[16][57], y4[16][32].
// Pregate: 192 threads own one (d,gate-row) each; weights in REGISTERS
// (global, L2-hot); y read as ds_read_b128 with 48-lane broadcast.
__global__ __launch_bounds__(256) void convpre_kernel(const float* __restrict__ x,
    const float* __restrict__ c1w1, const float* __restrict__ c1b1,
    const float* __restrict__ c1w2, const float* __restrict__ c1b2,
    const float* __restrict__ c2w1, const float* __restrict__ c2b1,
    const float* __restrict__ c2w2, const float* __restrict__ c2b2,
    const float* __restrict__ l10Wih, const float* __restrict__ l10b,
    const float* __restrict__ l20Wih, const float* __restrict__ l20b,
    float* __restrict__ pre,
    const float* __restrict__ fcw1, const float* __restrict__ fcw2,
    const float* __restrict__ fcw3, const float* __restrict__ fcb1,
    const float* __restrict__ fcb2, const float* __restrict__ fcb3,
    float* __restrict__ wpart, float* __restrict__ BC)
{
  __shared__ float sb[5072];
  int gb  = blockIdx.x;
  int tid = threadIdx.x;

  if (gb < 337){
    if (gb < 336){
      // wpartA: inline Wt tile (9x64 of fcw3@fcw2), then split-K over fcw1
      int s = gb / 21, jb = gb % 21;
      for (int i = tid; i < 576; i += 256){
        int o = i >> 6, n = i & 63;
        const float* f3 = fcw3 + o*192;
        const float* f2 = fcw2 + s*64 + n;
        float acc = 0.f;
        for (int p=0;p<192;p++) acc += f3[p]*f2[(size_t)p*1024];
        sb[i] = acc;
      }
      __syncthreads();
      int j = jb*256 + tid;
      float acc[9];
      #pragma unroll
      for (int o=0;o<9;o++) acc[o]=0.f;
      int nbase = s*64;
      #pragma unroll 4
      for (int n=0;n<64;n++){
        float v = fcw1[(size_t)(nbase+n)*5376 + j];
        #pragma unroll
        for (int o=0;o<9;o++) acc[o] += sb[o*64+n]*v;
      }
      #pragma unroll
      for (int o=0;o<9;o++) wpart[((size_t)s*9+o)*5376 + j] = acc[o];
    } else {
      // bcomp: BC[o] = fcb3[o] + fcw3[o,:] @ (fcb2 + fcw2@fcb1)
      if (tid < 192){
        const float* f2 = fcw2 + (size_t)tid*1024;
        float acc = 0.f;
        for (int n=0;n<1024;n++) acc += f2[n]*fcb1[n];
        sb[tid] = acc;
      }
      __syncthreads();
      if (tid < 9){
        float acc = fcb3[tid];
        const float* f3 = fcw3 + tid*192;
        for (int p=0;p<192;p++) acc += f3[p]*(fcb2[p]+sb[p]);
        BC[tid] = acc;
      }
    }
    return;
  }

  // -------- conv + pregate path: 16 rows per block --------
  float* xs4  = sb;          // [p][row][c] : p*912 + row*57 + c
  float* c1s  = sb + 3648;   // row*57 + cj
  float* y4   = sb + 4560;   // row*32 + j   (stride 32, b128-aligned)

  int blk = gb - 337;                 // 0..3583
  int branch = (blk >= 1792);
  int lblk = blk - branch*1792;
  int b  = lblk / 14;
  int t0 = (lblk - b*14)*16;
  size_t rbase = ((size_t)(branch*128 + b))*224 + t0;   // global x row
  size_t prow  = (size_t)b*224 + t0;                    // pre row within run

  const float* w1 = branch ? c2w1 : c1w1;
  const float* w2 = branch ? c2w2 : c1w2;
  float b1  = branch ? c2b1[0] : c1b1[0];
  float b2v = branch ? c2b2[0] : c1b2[0];
  const float* wih = branch ? l20Wih : l10Wih;   // (2,48,28)
  const float* bia = branch ? l20b   : l10b;     // (2,48)

  // stage x: 896 float4 -> phase-split LDS
  for (int i = tid; i < 896; i += 256){
    int row = i / 56, c = i - row*56;
    float4 v = *((const float4*)x + (rbase + row)*56 + c);
    int o = row*57 + c;
    xs4[o]          = v.x;
    xs4[912  + o]   = v.y;
    xs4[1824 + o]   = v.z;
    xs4[2736 + o]   = v.w;
  }
  __syncthreads();

  float w1r[8];
  #pragma unroll
  for (int kk=0;kk<8;kk++) w1r[kk]=w1[kk];

  // conv1 stride-4 pad-2 + relu: all LDS reads stride-1 across lanes
  for (int i = tid; i < 896; i += 256){
    int row = i / 56, cj = i - row*56;
    const float* xp = &xs4[row*57 + cj];
    float s = b1;
    if (cj >= 1){
      s += w1r[0]*xp[1824 - 1];
      s += w1r[1]*xp[2736 - 1];
    }
    s += w1r[2]*xp[0];
    s += w1r[3]*xp[912];
    s += w1r[4]*xp[1824];
    s += w1r[5]*xp[2736];
    if (cj <= 54){
      s += w1r[6]*xp[1];
      s += w1r[7]*xp[912 + 1];
    }
    c1s[row*57 + cj] = fmaxf(s, 0.f);
  }
  __syncthreads();

  // maxpool(4,2,pad1) + relu + conv3(pad1) + relu
  for (int i = tid; i < 448; i += 256){
    int row = i / 28, j = i - row*28;
    const float* cr = &c1s[row*57];
    float o = b2v;
    #pragma unroll
    for (int pi=0;pi<3;pi++){
      int p = j - 1 + pi;
      float pool = 0.f;
      if (p>=0 && p<28){
        int i0 = 2*p - 1;
        float m = -1e30f;
        #pragma unroll
        for (int q=0;q<4;q++){
          int ii = i0+q;
          if (ii>=0 && ii<56) m = fmaxf(m, cr[ii]);
        }
        pool = fmaxf(m, 0.f);
      }
      o += pool * w2[pi];
    }
    y4[row*32 + j] = fmaxf(o, 0.f);
  }
  __syncthreads();

  // pregate: 192 threads; t -> d = t/96, row = (t%96)%48, rrg = (t%96)/48
  if (tid < 192){
    int d   = tid / 96;
    int g96 = tid - d*96;
    int row = g96 % 48;
    int rrg = g96 / 48;             // 0 or 1 -> rr in [rrg*8, rrg*8+8)
    const float4* wr = (const float4*)(wih + (d*48 + row)*28);  // 112B-aligned
    float4 wv[7];
    #pragma unroll
    for (int q=0;q<7;q++) wv[q] = wr[q];
    float bias = bia[d*48 + row];
    int unit = row % 12, g = row / 12;
    float* prebase = pre + (size_t)(2*branch + d)*(TT*BB*48) + unit*4 + g;
    #pragma unroll
    for (int rq=0; rq<8; rq++){
      int rr = rrg*8 + rq;
      const float4* yv = (const float4*)&y4[rr*32];
      float acc = bias;
      #pragma unroll
      for (int q=0;q<7;q++){
        float4 yq = yv[q];
        acc += yq.x*wv[q].x + yq.y*wv[q].y + yq.z*wv[q].z + yq.w*wv[q].w;
      }
      prebase[(prow + rr)*48] = acc;
    }
  }
}

// -------- K2: layer-2 pre-gate GEMM (batch-major) + wpartB blocks --------
__global__ __launch_bounds__(256) void pregate2_kernel(
    const float* __restrict__ in,
    const float* __restrict__ wihA, const float* __restrict__ biasA,
    const float* __restrict__ wihB, const float* __restrict__ biasB,
    float* __restrict__ pre,
    const float* __restrict__ wpart, float* __restrict__ Wc)
{
  const int D = 24;
  __shared__ float sb[48*24 + 48];
  int gb  = blockIdx.x;
  int tid = threadIdx.x;

  if (gb < 189){
    int idx = gb*256 + tid;   // 189*256 = 48384 exactly
    float a = 0.f;
    #pragma unroll
    for (int s=0;s<16;s++) a += wpart[(size_t)s*48384 + idx];
    Wc[idx] = a;
    return;
  }

  int pgb = gb - 189;
  float* wL = sb;
  float* bL = sb + 48*D;
  int r = pgb / 1344;
  int lin = (pgb % 1344)*256 + tid;
  int br = r>>1, dir = r&1;
  const float* wih  = (br ? wihB  : wihA)  + dir*48*D;
  const float* bias = (br ? biasB : biasA) + dir*48;
  for (int i = tid; i < 48*D; i += 256) wL[i]=wih[i];
  if (tid < 48) bL[tid]=bias[tid];
  __syncthreads();
  int tb = lin/12;  int k = lin - tb*12;   // tb = b*224 + t (batch-major)
  const float* rowp = in + (size_t)br*688128 + (size_t)tb*D;
  float aI=bL[k], aF=bL[12+k], aG=bL[24+k], aO=bL[36+k];
  const float4* rp4 = (const float4*)rowp;
  #pragma unroll
  for (int d4=0; d4<D/4; d4++){
    float4 xv = rp4[d4];
    float4 wI = *(const float4*)&wL[(0*12+k)*D + d4*4];
    float4 wF = *(const float4*)&wL[(1*12+k)*D + d4*4];
    float4 wG = *(const float4*)&wL[(2*12+k)*D + d4*4];
    float4 wO = *(const float4*)&wL[(3*12+k)*D + d4*4];
    aI += xv.x*wI.x + xv.y*wI.y + xv.z*wI.z + xv.w*wI.w;
    aF += xv.x*wF.x + xv.y*wF.y + xv.z*wF.z + xv.w*wF.w;
    aG += xv.x*wG.x + xv.y*wG.y + xv.z*wG.z + xv.w*wG.w;
    aO += xv.x*wO.x + xv.y*wO.y + xv.z*wO.z + xv.w*wO.w;
  }
  float4* o = (float4*)(pre + (size_t)r*(TT*BB*48) + (size_t)tb*48 + k*4);
  *o = make_float4(aI,aF,aG,aO);
}

// ---------------- K3: LSTM scan, single-chain (R11 form) ------------------
#define LSTM_STEP(P, SS) { \
  float x1=rorN<1>(hv), x2=rorN<2>(hv), x3=rorN<3>(hv), x4=rorN<4>(hv), \
        x5=rorN<5>(hv), x6=rorN<6>(hv), x7=rorN<7>(hv), x8=rorN<8>(hv), \
        x9=rorN<9>(hv), x10=rorN<10>(hv), x11=rorN<11>(hv), x12=rorN<12>(hv), \
        x13=rorN<13>(hv), x14=rorN<14>(hv), x15=rorN<15>(hv); \
  v2f a0 = (P); \
  a0 += w[0]*(v2f){hv,hv};   a0 += w[1]*(v2f){x1,x1};   a0 += w[2]*(v2f){x2,x2};   a0 += w[3]*(v2f){x3,x3}; \
  v2f a1 = w[4]*(v2f){x4,x4};   a1 += w[5]*(v2f){x5,x5};   a1 += w[6]*(v2f){x6,x6};   a1 += w[7]*(v2f){x7,x7}; \
  v2f a2 = w[8]*(v2f){x8,x8};   a2 += w[9]*(v2f){x9,x9};   a2 += w[10]*(v2f){x10,x10}; a2 += w[11]*(v2f){x11,x11}; \
  v2f a3 = w[12]*(v2f){x12,x12}; a3 += w[13]*(v2f){x13,x13}; a3 += w[14]*(v2f){x14,x14}; a3 += w[15]*(v2f){x15,x15}; \
  v2f gg = (a0+a1)+(a2+a3); \
  v2f m  = gg*kmul; \
  v2f e  = { EXP2(m.x), EXP2(m.y) }; \
  e += (v2f){1.f,1.f}; \
  v2f d  = { rcpf(e.x), rcpf(e.y) }; \
  v2f res = ca*d + cb; \
  float p0 = res.x, p1 = res.x; swap32(p0, p1); \
  float q0 = res.y, q1 = res.y; swap32(q0, q1); \
  cst = fmaf(q0, cst, p0*p1); \
  float et = EXP2(cst*2.885390082f); \
  float dt = rcpf(et+1.f); \
  hv = q1*fmaf(-2.f, dt, 1.f); \
  hbuf[SS] = hv; }

#define FLUSH8 { \
  if (doSt){ \
    _Pragma("unroll") \
    for (int q=0;q<8;q++) outP[q*ostep] = hbuf[q]; \
  } \
  outP += 8*ostep; }

__global__ __launch_bounds__(64) __attribute__((amdgpu_waves_per_eu(1,1)))
void lstm_kernel(const float* __restrict__ pre,
    const float* __restrict__ whhA, const float* __restrict__ whhB,
    float* __restrict__ out)
{
  int blk  = blockIdx.x;
  int r    = blk >> 6;            // run 0..3 (64 blocks per run)
  int br   = r >> 1, dir = r & 1;
  int lane = threadIdx.x;
  int u    = lane & 15;
  int bh   = (lane >> 4) & 1;
  int rbit = lane >> 5;
  int keff = (u < 12) ? u : 11;
  int b    = (blk & 63)*2 + bh;
  const float* whh = (br ? whhB : whhA) + dir*48*12;

  v2f w[16];
  #pragma unroll
  for (int rr=0; rr<16; rr++){
    int j = (u - rr) & 15;
    bool vld = (j < 12) && (u < 12);
    int uw = (u < 12) ? u : 0;
    int jw = (j < 12) ? j : 0;
    float wa = whh[((rbit?24:0)  + uw)*12 + jw];
    float wb = whh[((rbit?36:12) + uw)*12 + jw];
    w[rr] = (v2f){ vld ? wa : 0.f, vld ? wb : 0.f };
  }
  const v2f kmul = rbit ? (v2f){2.885390082f, -1.442695041f}
                        : (v2f){-1.442695041f, -1.442695041f};
  const v2f ca   = rbit ? (v2f){-2.f, 1.f} : (v2f){1.f, 1.f};
  const v2f cb   = rbit ? (v2f){ 1.f, 0.f} : (v2f){0.f, 0.f};

  const float* preR = pre + (size_t)r*(TT*BB*48) + (size_t)b*(TT*48) + keff*4 + rbit*2;
  const int sstep = dir ? -48 : 48;
  int scb = dir ? 223*48 : 0;

  v2f pcur[8], pnext[8];
  #pragma unroll
  for (int i=0;i<8;i++) pcur[i]  = *(const v2f*)(preR + scb +  i   *sstep);
  #pragma unroll
  for (int i=0;i<8;i++) pnext[i] = *(const v2f*)(preR + scb + (i+8)*sstep);
  int lb = scb + 16*sstep;

  float hv = 0.f, cst = 0.f;
  float hbuf[8];
  const int ostep = dir ? -24 : 24;
  float* outP = out + (size_t)br*(BB*TT*24) + (size_t)b*TT*24 + dir*12 + u
              + (size_t)(dir ? 223 : 0)*24;
  const bool doSt = (rbit==0) && (u < 12);

  for (int c=0;c<14;c++){
    LSTM_STEP(pcur[0],0) LSTM_STEP(pcur[1],1) LSTM_STEP(pcur[2],2) LSTM_STEP(pcur[3],3)
    LSTM_STEP(pcur[4],4) LSTM_STEP(pcur[5],5) LSTM_STEP(pcur[6],6) LSTM_STEP(pcur[7],7)
    FLUSH8
    if (c < 13){
      #pragma unroll
      for (int i=0;i<8;i++) pcur[i] = *(const v2f*)(preR + lb + i*sstep);
      lb += 8*sstep;
    }
    LSTM_STEP(pnext[0],0) LSTM_STEP(pnext[1],1) LSTM_STEP(pnext[2],2) LSTM_STEP(pnext[3],3)
    LSTM_STEP(pnext[4],4) LSTM_STEP(pnext[5],5) LSTM_STEP(pnext[6],6) LSTM_STEP(pnext[7],7)
    FLUSH8
    if (c < 13){
      #pragma unroll
      for (int i=0;i<8;i++) pnext[i] = *(const v2f*)(preR + lb + i*sstep);
      lb += 8*sstep;
    }
  }
}

// ---------------- K6c: out[m][o] = (w1*o1+w2*o2) . Wc[o] + BC[o] ----------
__global__ void final_kernel(const float* __restrict__ o1, const float* __restrict__ o2,
    const float* __restrict__ Wc, const float* __restrict__ BC,
    const float* __restrict__ w1p, const float* __restrict__ w2p,
    float* __restrict__ out)
{
  int wid  = blockIdx.x*4 + (threadIdx.x>>6);
  int lane = threadIdx.x & 63;
  if (wid >= 128*9) return;
  int m = wid / 9, o = wid - m*9;
  float w1 = w1p[0], w2 = w2p[0];
  const float* r1 = o1 + (size_t)m*5376;
  const float* r2 = o2 + (size_t)m*5376;
  const float* wc = Wc + (size_t)o*5376;
  float acc = 0.f;
  for (int i=lane;i<5376;i+=64){
    acc += (w1*r1[i] + w2*r2[i]) * wc[i];
  }
  #pragma unroll
  for (int off=32;off;off>>=1) acc += __shfl_down(acc, off);
  if (lane==0) out[m*9+o] = acc + BC[o];
}

extern "C" void kernel_launch(void* const* d_in, const int* in_sizes, int n_in,
                              void* d_out, int out_size, void* d_ws, size_t ws_size,
                              hipStream_t stream) {
  (void)in_sizes; (void)n_in; (void)out_size; (void)ws_size;
  const float* x    = (const float*)d_in[0];
  const float* c1w1 = (const float*)d_in[1];
  const float* c1b1 = (const float*)d_in[2];
  const float* c1w2 = (const float*)d_in[3];
  const float* c1b2 = (const float*)d_in[4];
  const float* c2w1 = (const float*)d_in[5];
  const float* c2b1 = (const float*)d_in[6];
  const float* c2w2 = (const float*)d_in[7];
  const float* c2b2 = (const float*)d_in[8];
  const float* l10Wih = (const float*)d_in[9];
  const float* l10Whh = (const float*)d_in[10];
  const float* l10b   = (const float*)d_in[11];
  const float* l11Wih = (const float*)d_in[12];
  const float* l11Whh = (const float*)d_in[13];
  const float* l11b   = (const float*)d_in[14];
  const float* l20Wih = (const float*)d_in[15];
  const float* l20Whh = (const float*)d_in[16];
  const float* l20b   = (const float*)d_in[17];
  const float* l21Wih = (const float*)d_in[18];
  const float* l21Whh = (const float*)d_in[19];
  const float* l21b   = (const float*)d_in[20];
  const float* fcw1 = (const float*)d_in[21];
  const float* fcb1 = (const float*)d_in[22];
  const float* fcw2 = (const float*)d_in[23];
  const float* fcb2 = (const float*)d_in[24];
  const float* fcw3 = (const float*)d_in[25];
  const float* fcb3 = (const float*)d_in[26];
  const float* w1   = (const float*)d_in[27];
  const float* w2   = (const float*)d_in[28];
  float* out = (float*)d_out;

  float* ws  = (float*)d_ws;
  float* wpart = ws;                      // 774144
  float* pre  = ws  + 2*802816;           // 4 * 1376256
  float* ol0  = pre + 4*1376256;          // 2 * 688128
  float* ol1  = ol0 + 2*688128;           // 2 * 688128
  float* Wc   = ol1 + 2*688128;           // 48384
  float* BC   = Wc  + 48384;              // 9

  convpre_kernel<<<3921,256,0,stream>>>(x, c1w1,c1b1,c1w2,c1b2, c2w1,c2b1,c2w2,c2b2,
      l10Wih, l10b, l20Wih, l20b, pre,
      fcw1, fcw2, fcw3, fcb1, fcb2, fcb3, wpart, BC);
  lstm_kernel<<<256,64,0,stream>>>(pre, l10Whh, l20Whh, ol0);
  pregate2_kernel<<<5565,256,0,stream>>>(ol0, l11Wih, l11b, l21Wih, l21b, pre, wpart, Wc);
  lstm_kernel<<<256,64,0,stream>>>(pre, l11Whh, l21Whh, ol1);
  final_kernel<<<288,256,0,stream>>>(ol1, ol1+688128, Wc, BC, w1, w2, out);
}

// Round 16
// 166.860 us; speedup vs baseline: 1.3766x; 1.0912x over previous
//
#include <hip/hip_runtime.h>

#define BB 128
#define TT 224
#define LL 224

typedef float v2f __attribute__((ext_vector_type(2)));

__device__ __forceinline__ float rcpf(float x){ return __builtin_amdgcn_rcpf(x); }

#if __has_builtin(__builtin_amdgcn_exp2f)
#define EXP2(x) __builtin_amdgcn_exp2f(x)
#else
#define EXP2(x) __expf((x)*0.6931471805599453f)
#endif

// DPP row rotate-right by N: dst[k] = src[(k-N)&15] within each 16-lane row
template<int N>
__device__ __forceinline__ float rorN(float x){
  int xi = __builtin_bit_cast(int, x);
  xi = __builtin_amdgcn_update_dpp(xi, xi, 0x120 + N, 0xf, 0xf, false);
  return __builtin_bit_cast(float, xi);
}

// v_permlane32_swap_b32: with a==b==x -> a'=low-half bcast, b'=high-half bcast
__device__ __forceinline__ void swap32(float& a, float& b){
  asm volatile("s_nop 1\n\tv_permlane32_swap_b32 %0, %1\n\ts_nop 1"
               : "+v"(a), "+v"(b));
}

// ---- K1: conv chain + layer-1 pre-gate (pure; FC work moved out) ---------
// 3584 blocks: conv 16 rows -> gates for both dirs of branch.
// LDS (floats): xs4[4][16][57] phase-split x, c1s[16][57], y4[16][32].
__global__ __launch_bounds__(256) void convpre_kernel(const float* __restrict__ x,
    const float* __restrict__ c1w1, const float* __restrict__ c1b1,
    const float* __restrict__ c1w2, const float* __restrict__ c1b2,
    const float* __restrict__ c2w1, const float* __restrict__ c2b1,
    const float* __restrict__ c2w2, const float* __restrict__ c2b2,
    const float* __restrict__ l10Wih, const float* __restrict__ l10b,
    const float* __restrict__ l20Wih, const float* __restrict__ l20b,
    float* __restrict__ pre)
{
  __shared__ float sb[5072];
  int gb  = blockIdx.x;
  int tid = threadIdx.x;

  float* xs4  = sb;          // [p][row][c] : p*912 + row*57 + c
  float* c1s  = sb + 3648;   // row*57 + cj
  float* y4   = sb + 4560;   // row*32 + j   (stride 32, b128-aligned)

  int blk = gb;                       // 0..3583
  int branch = (blk >= 1792);
  int lblk = blk - branch*1792;
  int b  = lblk / 14;
  int t0 = (lblk - b*14)*16;
  size_t rbase = ((size_t)(branch*128 + b))*224 + t0;   // global x row
  size_t prow  = (size_t)b*224 + t0;                    // pre row within run

  const float* w1 = branch ? c2w1 : c1w1;
  const float* w2 = branch ? c2w2 : c1w2;
  float b1  = branch ? c2b1[0] : c1b1[0];
  float b2v = branch ? c2b2[0] : c1b2[0];
  const float* wih = branch ? l20Wih : l10Wih;   // (2,48,28)
  const float* bia = branch ? l20b   : l10b;     // (2,48)

  // stage x: 896 float4 -> phase-split LDS
  for (int i = tid; i < 896; i += 256){
    int row = i / 56, c = i - row*56;
    float4 v = *((const float4*)x + (rbase + row)*56 + c);
    int o = row*57 + c;
    xs4[o]          = v.x;
    xs4[912  + o]   = v.y;
    xs4[1824 + o]   = v.z;
    xs4[2736 + o]   = v.w;
  }
  __syncthreads();

  float w1r[8];
  #pragma unroll
  for (int kk=0;kk<8;kk++) w1r[kk]=w1[kk];

  // conv1 stride-4 pad-2 + relu: all LDS reads stride-1 across lanes
  for (int i = tid; i < 896; i += 256){
    int row = i / 56, cj = i - row*56;
    const float* xp = &xs4[row*57 + cj];
    float s = b1;
    if (cj >= 1){
      s += w1r[0]*xp[1824 - 1];
      s += w1r[1]*xp[2736 - 1];
    }
    s += w1r[2]*xp[0];
    s += w1r[3]*xp[912];
    s += w1r[4]*xp[1824];
    s += w1r[5]*xp[2736];
    if (cj <= 54){
      s += w1r[6]*xp[1];
      s += w1r[7]*xp[912 + 1];
    }
    c1s[row*57 + cj] = fmaxf(s, 0.f);
  }
  __syncthreads();

  // maxpool(4,2,pad1) + relu + conv3(pad1) + relu
  for (int i = tid; i < 448; i += 256){
    int row = i / 28, j = i - row*28;
    const float* cr = &c1s[row*57];
    float o = b2v;
    #pragma unroll
    for (int pi=0;pi<3;pi++){
      int p = j - 1 + pi;
      float pool = 0.f;
      if (p>=0 && p<28){
        int i0 = 2*p - 1;
        float m = -1e30f;
        #pragma unroll
        for (int q=0;q<4;q++){
          int ii = i0+q;
          if (ii>=0 && ii<56) m = fmaxf(m, cr[ii]);
        }
        pool = fmaxf(m, 0.f);
      }
      o += pool * w2[pi];
    }
    y4[row*32 + j] = fmaxf(o, 0.f);
  }
  __syncthreads();

  // pregate: 192 threads; weights in registers (global, L2-hot)
  if (tid < 192){
    int d   = tid / 96;
    int g96 = tid - d*96;
    int row = g96 % 48;
    int rrg = g96 / 48;
    const float4* wr = (const float4*)(wih + (d*48 + row)*28);  // 112B-aligned
    float4 wv[7];
    #pragma unroll
    for (int q=0;q<7;q++) wv[q] = wr[q];
    float bias = bia[d*48 + row];
    int unit = row % 12, g = row / 12;
    float* prebase = pre + (size_t)(2*branch + d)*(TT*BB*48) + unit*4 + g;
    #pragma unroll
    for (int rq=0; rq<8; rq++){
      int rr = rrg*8 + rq;
      const float4* yv = (const float4*)&y4[rr*32];
      float acc = bias;
      #pragma unroll
      for (int q=0;q<7;q++){
        float4 yq = yv[q];
        acc += yq.x*wv[q].x + yq.y*wv[q].y + yq.z*wv[q].z + yq.w*wv[q].w;
      }
      prebase[(prow + rr)*48] = acc;
    }
  }
}

// ---------------- K3: LSTM scan + shadow FC blocks ------------------------
// blocks [0,256): lstm single-chain (R11 form, 1 wave, 1 wave/EU).
// blocks [256, 256+1344): wpartA-64 (runs in the idle EU slots under the
// lstm shadow): per (s, j64) computes Wt tile (9x64) with SGPR-broadcast
// fcw3 and coalesced fcw2 column loads, then split-K partials over fcw1;
// j64==0 blocks also emit BCpart[s][o] (kills the serial bcomp straggler).
#define LSTM_STEP(P, SS) { \
  float x1=rorN<1>(hv), x2=rorN<2>(hv), x3=rorN<3>(hv), x4=rorN<4>(hv), \
        x5=rorN<5>(hv), x6=rorN<6>(hv), x7=rorN<7>(hv), x8=rorN<8>(hv), \
        x9=rorN<9>(hv), x10=rorN<10>(hv), x11=rorN<11>(hv), x12=rorN<12>(hv), \
        x13=rorN<13>(hv), x14=rorN<14>(hv), x15=rorN<15>(hv); \
  v2f a0 = (P); \
  a0 += w[0]*(v2f){hv,hv};   a0 += w[1]*(v2f){x1,x1};   a0 += w[2]*(v2f){x2,x2};   a0 += w[3]*(v2f){x3,x3}; \
  v2f a1 = w[4]*(v2f){x4,x4};   a1 += w[5]*(v2f){x5,x5};   a1 += w[6]*(v2f){x6,x6};   a1 += w[7]*(v2f){x7,x7}; \
  v2f a2 = w[8]*(v2f){x8,x8};   a2 += w[9]*(v2f){x9,x9};   a2 += w[10]*(v2f){x10,x10}; a2 += w[11]*(v2f){x11,x11}; \
  v2f a3 = w[12]*(v2f){x12,x12}; a3 += w[13]*(v2f){x13,x13}; a3 += w[14]*(v2f){x14,x14}; a3 += w[15]*(v2f){x15,x15}; \
  v2f gg = (a0+a1)+(a2+a3); \
  v2f m  = gg*kmul; \
  v2f e  = { EXP2(m.x), EXP2(m.y) }; \
  e += (v2f){1.f,1.f}; \
  v2f d  = { rcpf(e.x), rcpf(e.y) }; \
  v2f res = ca*d + cb; \
  float p0 = res.x, p1 = res.x; swap32(p0, p1); \
  float q0 = res.y, q1 = res.y; swap32(q0, q1); \
  cst = fmaf(q0, cst, p0*p1); \
  float et = EXP2(cst*2.885390082f); \
  float dt = rcpf(et+1.f); \
  hv = q1*fmaf(-2.f, dt, 1.f); \
  hbuf[SS] = hv; }

#define FLUSH8 { \
  if (doSt){ \
    _Pragma("unroll") \
    for (int q=0;q<8;q++) outP[q*ostep] = hbuf[q]; \
  } \
  outP += 8*ostep; }

__global__ __launch_bounds__(64) __attribute__((amdgpu_waves_per_eu(1,1)))
void lstm_kernel(const float* __restrict__ pre,
    const float* __restrict__ whhA, const float* __restrict__ whhB,
    float* __restrict__ out,
    const float* __restrict__ fcw1, const float* __restrict__ fcw2,
    const float* __restrict__ fcw3, const float* __restrict__ fcb1,
    float* __restrict__ wpart, float* __restrict__ BCpart)
{
  __shared__ float wt[576];
  int blk  = blockIdx.x;
  int lane = threadIdx.x;

  if (blk >= 256){
    // ---- wpartA-64 (shadow FC) ----
    int xb  = blk - 256;          // 0..1343
    int s   = xb / 84;            // K-chunk 0..15
    int j64 = xb % 84;            // 64-wide j group
    // Wt tile: acc[q] over p with SGPR-broadcast fcw3, coalesced fcw2 cols
    {
      float acc[9];
      #pragma unroll
      for (int q=0;q<9;q++) acc[q]=0.f;
      const float* f2 = fcw2 + s*64 + lane;
      for (int p=0;p<192;p++){
        float v = f2[(size_t)p*1024];
        #pragma unroll
        for (int q=0;q<9;q++) acc[q] += fcw3[q*192+p]*v;
      }
      #pragma unroll
      for (int q=0;q<9;q++) wt[q*64+lane] = acc[q];
    }
    __syncthreads();
    int j = j64*64 + lane;
    float acc[9];
    #pragma unroll
    for (int o=0;o<9;o++) acc[o]=0.f;
    int nbase = s*64;
    #pragma unroll 4
    for (int n=0;n<64;n++){
      float v = fcw1[(size_t)(nbase+n)*5376 + j];
      #pragma unroll
      for (int o=0;o<9;o++) acc[o] += wt[o*64+n]*v;
    }
    #pragma unroll
    for (int o=0;o<9;o++) wpart[((size_t)s*9+o)*5376 + j] = acc[o];
    if (j64 == 0 && lane < 9){
      float bcp = 0.f;
      for (int n=0;n<64;n++) bcp += wt[lane*64+n]*fcb1[nbase+n];
      BCpart[s*9+lane] = bcp;
    }
    return;
  }

  // ---- lstm chain ----
  int r    = blk >> 6;            // run 0..3 (64 blocks per run)
  int br   = r >> 1, dir = r & 1;
  int u    = lane & 15;
  int bh   = (lane >> 4) & 1;
  int rbit = lane >> 5;
  int keff = (u < 12) ? u : 11;
  int b    = (blk & 63)*2 + bh;
  const float* whh = (br ? whhB : whhA) + dir*48*12;

  v2f w[16];
  #pragma unroll
  for (int rr=0; rr<16; rr++){
    int j = (u - rr) & 15;
    bool vld = (j < 12) && (u < 12);
    int uw = (u < 12) ? u : 0;
    int jw = (j < 12) ? j : 0;
    float wa = whh[((rbit?24:0)  + uw)*12 + jw];
    float wb = whh[((rbit?36:12) + uw)*12 + jw];
    w[rr] = (v2f){ vld ? wa : 0.f, vld ? wb : 0.f };
  }
  const v2f kmul = rbit ? (v2f){2.885390082f, -1.442695041f}
                        : (v2f){-1.442695041f, -1.442695041f};
  const v2f ca   = rbit ? (v2f){-2.f, 1.f} : (v2f){1.f, 1.f};
  const v2f cb   = rbit ? (v2f){ 1.f, 0.f} : (v2f){0.f, 0.f};

  const float* preR = pre + (size_t)r*(TT*BB*48) + (size_t)b*(TT*48) + keff*4 + rbit*2;
  const int sstep = dir ? -48 : 48;
  int scb = dir ? 223*48 : 0;

  v2f pcur[8], pnext[8];
  #pragma unroll
  for (int i=0;i<8;i++) pcur[i]  = *(const v2f*)(preR + scb +  i   *sstep);
  #pragma unroll
  for (int i=0;i<8;i++) pnext[i] = *(const v2f*)(preR + scb + (i+8)*sstep);
  int lb = scb + 16*sstep;

  float hv = 0.f, cst = 0.f;
  float hbuf[8];
  const int ostep = dir ? -24 : 24;
  float* outP = out + (size_t)br*(BB*TT*24) + (size_t)b*TT*24 + dir*12 + u
              + (size_t)(dir ? 223 : 0)*24;
  const bool doSt = (rbit==0) && (u < 12);

  for (int c=0;c<14;c++){
    LSTM_STEP(pcur[0],0) LSTM_STEP(pcur[1],1) LSTM_STEP(pcur[2],2) LSTM_STEP(pcur[3],3)
    LSTM_STEP(pcur[4],4) LSTM_STEP(pcur[5],5) LSTM_STEP(pcur[6],6) LSTM_STEP(pcur[7],7)
    FLUSH8
    if (c < 13){
      #pragma unroll
      for (int i=0;i<8;i++) pcur[i] = *(const v2f*)(preR + lb + i*sstep);
      lb += 8*sstep;
    }
    LSTM_STEP(pnext[0],0) LSTM_STEP(pnext[1],1) LSTM_STEP(pnext[2],2) LSTM_STEP(pnext[3],3)
    LSTM_STEP(pnext[4],4) LSTM_STEP(pnext[5],5) LSTM_STEP(pnext[6],6) LSTM_STEP(pnext[7],7)
    FLUSH8
    if (c < 13){
      #pragma unroll
      for (int i=0;i<8;i++) pnext[i] = *(const v2f*)(preR + lb + i*sstep);
      lb += 8*sstep;
    }
  }
}

// -------- K2: layer-2 pre-gate GEMM + wpartB + BC-reduce blocks ----------
__global__ __launch_bounds__(256) void pregate2_kernel(
    const float* __restrict__ in,
    const float* __restrict__ wihA, const float* __restrict__ biasA,
    const float* __restrict__ wihB, const float* __restrict__ biasB,
    float* __restrict__ pre,
    const float* __restrict__ wpart, float* __restrict__ Wc,
    const float* __restrict__ fcw3, const float* __restrict__ fcb2,
    const float* __restrict__ fcb3, const float* __restrict__ BCpart,
    float* __restrict__ BC)
{
  const int D = 24;
  __shared__ float sb[48*24 + 48];
  int gb  = blockIdx.x;
  int tid = threadIdx.x;

  if (gb < 189){
    int idx = gb*256 + tid;   // 189*256 = 48384 exactly
    float a = 0.f;
    #pragma unroll
    for (int s=0;s<16;s++) a += wpart[(size_t)s*48384 + idx];
    Wc[idx] = a;
    return;
  }
  if (gb == 189){
    if (tid < 9){
      float acc = fcb3[tid];
      const float* f3 = fcw3 + tid*192;
      for (int p=0;p<192;p++) acc += f3[p]*fcb2[p];
      #pragma unroll
      for (int s=0;s<16;s++) acc += BCpart[s*9+tid];
      BC[tid] = acc;
    }
    return;
  }

  int pgb = gb - 190;
  float* wL = sb;
  float* bL = sb + 48*D;
  int r = pgb / 1344;
  int lin = (pgb % 1344)*256 + tid;
  int br = r>>1, dir = r&1;
  const float* wih  = (br ? wihB  : wihA)  + dir*48*D;
  const float* bias = (br ? biasB : biasA) + dir*48;
  for (int i = tid; i < 48*D; i += 256) wL[i]=wih[i];
  if (tid < 48) bL[tid]=bias[tid];
  __syncthreads();
  int tb = lin/12;  int k = lin - tb*12;   // tb = b*224 + t (batch-major)
  const float* rowp = in + (size_t)br*688128 + (size_t)tb*D;
  float aI=bL[k], aF=bL[12+k], aG=bL[24+k], aO=bL[36+k];
  const float4* rp4 = (const float4*)rowp;
  #pragma unroll
  for (int d4=0; d4<D/4; d4++){
    float4 xv = rp4[d4];
    float4 wI = *(const float4*)&wL[(0*12+k)*D + d4*4];
    float4 wF = *(const float4*)&wL[(1*12+k)*D + d4*4];
    float4 wG = *(const float4*)&wL[(2*12+k)*D + d4*4];
    float4 wO = *(const float4*)&wL[(3*12+k)*D + d4*4];
    aI += xv.x*wI.x + xv.y*wI.y + xv.z*wI.z + xv.w*wI.w;
    aF += xv.x*wF.x + xv.y*wF.y + xv.z*wF.z + xv.w*wF.w;
    aG += xv.x*wG.x + xv.y*wG.y + xv.z*wG.z + xv.w*wG.w;
    aO += xv.x*wO.x + xv.y*wO.y + xv.z*wO.z + xv.w*wO.w;
  }
  float4* o = (float4*)(pre + (size_t)r*(TT*BB*48) + (size_t)tb*48 + k*4);
  *o = make_float4(aI,aF,aG,aO);
}

// ---------------- K6c: out[m][o] = (w1*o1+w2*o2) . Wc[o] + BC[o] ----------
__global__ void final_kernel(const float* __restrict__ o1, const float* __restrict__ o2,
    const float* __restrict__ Wc, const float* __restrict__ BC,
    const float* __restrict__ w1p, const float* __restrict__ w2p,
    float* __restrict__ out)
{
  int wid  = blockIdx.x*4 + (threadIdx.x>>6);
  int lane = threadIdx.x & 63;
  if (wid >= 128*9) return;
  int m = wid / 9, o = wid - m*9;
  float w1 = w1p[0], w2 = w2p[0];
  const float* r1 = o1 + (size_t)m*5376;
  const float* r2 = o2 + (size_t)m*5376;
  const float* wc = Wc + (size_t)o*5376;
  float acc = 0.f;
  for (int i=lane;i<5376;i+=64){
    acc += (w1*r1[i] + w2*r2[i]) * wc[i];
  }
  #pragma unroll
  for (int off=32;off;off>>=1) acc += __shfl_down(acc, off);
  if (lane==0) out[m*9+o] = acc + BC[o];
}

extern "C" void kernel_launch(void* const* d_in, const int* in_sizes, int n_in,
                              void* d_out, int out_size, void* d_ws, size_t ws_size,
                              hipStream_t stream) {
  (void)in_sizes; (void)n_in; (void)out_size; (void)ws_size;
  const float* x    = (const float*)d_in[0];
  const float* c1w1 = (const float*)d_in[1];
  const float* c1b1 = (const float*)d_in[2];
  const float* c1w2 = (const float*)d_in[3];
  const float* c1b2 = (const float*)d_in[4];
  const float* c2w1 = (const float*)d_in[5];
  const float* c2b1 = (const float*)d_in[6];
  const float* c2w2 = (const float*)d_in[7];
  const float* c2b2 = (const float*)d_in[8];
  const float* l10Wih = (const float*)d_in[9];
  const float* l10Whh = (const float*)d_in[10];
  const float* l10b   = (const float*)d_in[11];
  const float* l11Wih = (const float*)d_in[12];
  const float* l11Whh = (const float*)d_in[13];
  const float* l11b   = (const float*)d_in[14];
  const float* l20Wih = (const float*)d_in[15];
  const float* l20Whh = (const float*)d_in[16];
  const float* l20b   = (const float*)d_in[17];
  const float* l21Wih = (const float*)d_in[18];
  const float* l21Whh = (const float*)d_in[19];
  const float* l21b   = (const float*)d_in[20];
  const float* fcw1 = (const float*)d_in[21];
  const float* fcb1 = (const float*)d_in[22];
  const float* fcw2 = (const float*)d_in[23];
  const float* fcb2 = (const float*)d_in[24];
  const float* fcw3 = (const float*)d_in[25];
  const float* fcb3 = (const float*)d_in[26];
  const float* w1   = (const float*)d_in[27];
  const float* w2   = (const float*)d_in[28];
  float* out = (float*)d_out;

  float* ws  = (float*)d_ws;
  float* wpart = ws;                      // 774144
  float* pre  = ws  + 2*802816;           // 4 * 1376256
  float* ol0  = pre + 4*1376256;          // 2 * 688128
  float* ol1  = ol0 + 2*688128;           // 2 * 688128
  float* Wc   = ol1 + 2*688128;           // 48384
  float* BC   = Wc  + 48384;              // 9
  float* BCpart = BC + 9;                 // 144

  convpre_kernel<<<3584,256,0,stream>>>(x, c1w1,c1b1,c1w2,c1b2, c2w1,c2b1,c2w2,c2b2,
      l10Wih, l10b, l20Wih, l20b, pre);
  lstm_kernel<<<1600,64,0,stream>>>(pre, l10Whh, l20Whh, ol0,
      fcw1, fcw2, fcw3, fcb1, wpart, BCpart);
  pregate2_kernel<<<5566,256,0,stream>>>(ol0, l11Wih, l11b, l21Wih, l21b, pre, wpart, Wc,
      fcw3, fcb2, fcb3, BCpart, BC);
  lstm_kernel<<<256,64,0,stream>>>(pre, l11Whh, l21Whh, ol1,
      fcw1, fcw2, fcw3, fcb1, wpart, BCpart);
  final_kernel<<<288,256,0,stream>>>(ol1, ol1+688128, Wc, BC, w1, w2, out);
}